// Round 18
// baseline (922.222 us; speedup 1.0000x reference)
//
#include <hip/hip_runtime.h>
#include <hip/hip_bf16.h>

typedef __attribute__((ext_vector_type(8))) short bf16x8;
typedef __attribute__((ext_vector_type(4))) float f32x4;

__device__ __forceinline__ float sigf(float x){ return 1.0f/(1.0f+expf(-x)); }
__device__ __forceinline__ int clampi(int v, int lo, int hi){ return v<lo?lo:(v>hi?hi:v); }
__device__ __forceinline__ unsigned short f2b(float f){
    __hip_bfloat16 h = __float2bfloat16(f);
    return *reinterpret_cast<unsigned short*>(&h);
}
__device__ __forceinline__ float us2f(unsigned short u){ return __uint_as_float(((unsigned)u)<<16); }

__device__ __forceinline__ void gload16(const void* g, void* l){
    __builtin_amdgcn_global_load_lds((const __attribute__((address_space(1))) void*)g,
                                     (__attribute__((address_space(3))) void*)l, 16, 0, 0);
}

// ---- int64/int32 tolerant index conversion ----
__global__ void k_cvt(const int* __restrict__ src, int* __restrict__ dst, int n,
                      const int* __restrict__ det)
{
    int i = blockIdx.x*blockDim.x + threadIdx.x;
    if (i >= n) return;
    int stride = (det[1] == 0) ? 2 : 1;
    dst[i] = src[(size_t)i*stride];
}

__global__ void k_wt(const float* __restrict__ W, unsigned short* __restrict__ Wt,
                     int N, int kshift, int kmask, int total)
{
    int idx = blockIdx.x*blockDim.x + threadIdx.x;
    if (idx >= total) return;
    int n = idx >> kshift, k = idx & kmask;
    Wt[idx] = f2b(W[(size_t)k*N + n]);
}

__global__ void k_wt2(const float* __restrict__ W, unsigned short* __restrict__ Whi,
                      unsigned short* __restrict__ Wlo, int N, int kshift, int kmask, int total)
{
    int idx = blockIdx.x*blockDim.x + threadIdx.x;
    if (idx >= total) return;
    int n = idx >> kshift, k = idx & kmask;
    float v = W[(size_t)k*N + n];
    unsigned short hi = f2b(v);
    Whi[idx] = hi;
    Wlo[idx] = f2b(v - us2f(hi));
}

// ---------------- init projections ----------------
__global__ void k_proj5(const float* __restrict__ X, const float* __restrict__ W,
                        const float* __restrict__ bias,
                        const int* __restrict__ gidx, const int* __restrict__ sidx,
                        float* __restrict__ out, unsigned short* __restrict__ outBf,
                        float* __restrict__ out2, unsigned short* __restrict__ out2Bf,
                        int M, int nrows, int nodes)
{
    int t = blockIdx.x*blockDim.x + threadIdx.x;
    int i = t >> 7, j = t & 127;
    if (i >= M) return;
    int src = gidx ? clampi(gidx[i]-1, 0, nrows-1) : i;
    const float* xp = X + (size_t)src*5;
    float acc = bias[j];
#pragma unroll
    for (int k=0;k<5;k++) acc += xp[k] * W[k*128+j];
    int dr = sidx ? clampi(sidx[i], 0, nodes-1) : i;
    if (out)   out[(size_t)dr*128 + j] = acc;
    if (outBf) outBf[(size_t)dr*128 + j] = f2b(acc);
    if (out2)  out2[(size_t)i*128 + j] = acc;
    if (out2Bf) out2Bf[(size_t)i*128 + j] = f2b(acc);
}

// ---------------- f32 tiled GEMM (readout heads only) ----------------
__launch_bounds__(256)
__global__ void k_mm(const float* __restrict__ A0, int lda,
                     const float* __restrict__ B, int ldb,
                     const float* __restrict__ bias, float* __restrict__ C,
                     int M, int N, int K, int relu, float scale, int accum)
{
    __shared__ float As[16][132];
    __shared__ float Bs[16][132];
    int tid = threadIdx.x;
    int tx = tid & 15, ty = tid >> 4;
    int row0 = blockIdx.y * 128, col0 = blockIdx.x * 128;
    float acc[8][8] = {};
    for (int k0 = 0; k0 < K; k0 += 16){
#pragma unroll
        for (int q = 0; q < 2; ++q){
            int idx = tid + q*256;
            int r = idx >> 2, k4 = (idx & 3) * 4;
            const float* src = A0 + (size_t)(row0+r)*lda + k0 + k4;
            float4 v = *reinterpret_cast<const float4*>(src);
            As[k4+0][r]=v.x; As[k4+1][r]=v.y; As[k4+2][r]=v.z; As[k4+3][r]=v.w;
        }
#pragma unroll
        for (int q = 0; q < 2; ++q){
            int idx = tid + q*256;
            int kb = idx >> 5, n4 = (idx & 31) * 4;
            float4 v = *reinterpret_cast<const float4*>(B + (size_t)(k0+kb)*ldb + col0 + n4);
            *reinterpret_cast<float4*>(&Bs[kb][n4]) = v;
        }
        __syncthreads();
#pragma unroll
        for (int k = 0; k < 16; ++k){
            float a[8], b[8];
            *(float4*)&a[0] = *(const float4*)&As[k][ty*8];
            *(float4*)&a[4] = *(const float4*)&As[k][ty*8+4];
            *(float4*)&b[0] = *(const float4*)&Bs[k][tx*8];
            *(float4*)&b[4] = *(const float4*)&Bs[k][tx*8+4];
#pragma unroll
            for (int i=0;i<8;i++)
#pragma unroll
                for (int j=0;j<8;j++) acc[i][j] += a[i]*b[j];
        }
        __syncthreads();
    }
    float bb[8];
#pragma unroll
    for (int j=0;j<8;j++) bb[j] = bias ? bias[col0+tx*8+j] : 0.f;
#pragma unroll
    for (int i=0;i<8;i++){
        float* cp = C + (size_t)(row0+ty*8+i)*N + col0 + tx*8;
#pragma unroll
        for (int jq=0;jq<2;jq++){
            float4 prev = accum ? *(const float4*)(cp+jq*4) : make_float4(0,0,0,0);
            float o[4];
#pragma unroll
            for (int c=0;c<4;c++){
                float u = acc[i][jq*4+c] + bb[jq*4+c];
                if (relu) u = fmaxf(u,0.f);
                o[c] = (&prev.x)[c] + scale*u;
            }
            *(float4*)(cp+jq*4) = make_float4(o[0],o[1],o[2],o[3]);
        }
    }
}

// ---------------- pipelined bf16 MFMA GEMM body (counted vmcnt, 2-barrier) ----------------
struct MJob {
    const unsigned short *A0, *A1;
    const int *i0, *i1;
    const unsigned short *Wt;
    const float *bias;
    void *C;
    int N, K, epi, nrow;
    float scale;
};

#define MM2_SMEM 67840

__device__ __forceinline__ void mm2_body(const MJob J, int bid, char* smem)
{
    unsigned short* AsB = (unsigned short*)smem;
    unsigned short* BsB = AsB + 16384;
    int tid = threadIdx.x;
    int l = tid & 63, w = tid >> 6;
    int wr = w >> 1, wc = w & 1;
    int row0 = (bid % J.nrow) * 128, col0 = (bid / J.nrow) * 128;
    int nK = J.K >> 6;

    f32x4 acc[4][4];
#pragma unroll
    for (int m=0;m<4;m++)
#pragma unroll
        for (int n=0;n<4;n++) acc[m][n] = (f32x4){0.f,0.f,0.f,0.f};

    auto stage = [&](int buf, int k0){
        unsigned short* As = AsB + buf*8192;
        unsigned short* Bs = BsB + buf*8192;
#pragma unroll
        for (int q=0;q<4;q++){
            int slot = q*256 + w*64 + l;
            int r = slot >> 3, c8 = slot & 7;
            int g8 = c8 ^ (r & 7);
            int row; const unsigned short* base; int kl;
            if (k0 < 128){ row = J.i0 ? J.i0[row0+r] : (row0+r); base = J.A0; kl = k0; }
            else         { row = J.i1 ? J.i1[row0+r] : (row0+r); base = J.A1; kl = k0-128; }
            const char* g = (const char*)(base + (size_t)row*128 + kl) + g8*16;
            gload16(g, (void*)&As[(size_t)(q*256 + w*64)*8]);
        }
#pragma unroll
        for (int q=0;q<4;q++){
            int slot = q*256 + w*64 + l;
            int n = slot >> 3, kc = slot & 7;
            int g8 = kc ^ (n & 7);
            const char* g = (const char*)(J.Wt + (size_t)(col0+n)*J.K + k0) + g8*16;
            gload16(g, (void*)&Bs[(size_t)(q*256 + w*64)*8]);
        }
    };

    stage(0, 0);
    for (int ks=0; ks<nK; ++ks){
        int cur = ks & 1;
        if (ks+1 < nK){
            stage(cur^1, (ks+1)*64);
            asm volatile("s_waitcnt vmcnt(8)" ::: "memory");
        } else {
            asm volatile("s_waitcnt vmcnt(0)" ::: "memory");
        }
        __builtin_amdgcn_s_barrier();
        __builtin_amdgcn_sched_barrier(0);
        unsigned short* As = AsB + cur*8192;
        unsigned short* Bs = BsB + cur*8192;
#pragma unroll
        for (int kk = 0; kk < 2; ++kk){
            int ek = kk*32 + (l >> 4) * 8;
            bf16x8 af[4], bf[4];
#pragma unroll
            for (int m=0;m<4;m++){
                int r = wr*64 + m*16 + (l & 15);
                af[m] = *reinterpret_cast<const bf16x8*>(&As[r*64 + (ek ^ ((r & 7) << 3))]);
            }
#pragma unroll
            for (int n=0;n<4;n++){
                int c = wc*64 + n*16 + (l & 15);
                bf[n] = *reinterpret_cast<const bf16x8*>(&Bs[c*64 + (ek ^ ((c & 7) << 3))]);
            }
#pragma unroll
            for (int m=0;m<4;m++)
#pragma unroll
                for (int n=0;n<4;n++)
                    acc[m][n] = __builtin_amdgcn_mfma_f32_16x16x32_bf16(af[m], bf[n], acc[m][n], 0, 0, 0);
        }
        __builtin_amdgcn_sched_barrier(0);
        __builtin_amdgcn_s_barrier();
    }

    if (J.epi == 0){
        float* Ct = (float*)smem;
#pragma unroll
        for (int m=0;m<4;m++){
#pragma unroll
            for (int v=0;v<4;v++){
                int rl = wr*64 + m*16 + (l >> 4)*4 + v;
#pragma unroll
                for (int n=0;n<4;n++){
                    int c = wc*64 + n*16 + (l & 15);
                    Ct[rl*132 + c] = J.scale*acc[m][n][v] + (J.bias ? J.bias[col0+c] : 0.f);
                }
            }
        }
        __syncthreads();
#pragma unroll
        for (int q=0;q<16;q++){
            int idx = tid + q*256;
            int r = idx >> 5, c4 = (idx & 31)*4;
            float4 v = *reinterpret_cast<const float4*>(&Ct[r*132 + c4]);
            *reinterpret_cast<float4*>((float*)J.C + (size_t)(row0+r)*J.N + col0 + c4) = v;
        }
    } else {
        unsigned short* Cb = (unsigned short*)smem;
#pragma unroll
        for (int m=0;m<4;m++){
#pragma unroll
            for (int v=0;v<4;v++){
                int rl = wr*64 + m*16 + (l >> 4)*4 + v;
#pragma unroll
                for (int n=0;n<4;n++){
                    int c = wc*64 + n*16 + (l & 15);
                    Cb[rl*136 + c] = f2b(J.scale*acc[m][n][v] + (J.bias ? J.bias[col0+c] : 0.f));
                }
            }
        }
        __syncthreads();
#pragma unroll
        for (int q=0;q<8;q++){
            int idx = tid + q*256;
            int r = idx >> 4, c8 = (idx & 15)*8;
            uint4 v = *reinterpret_cast<const uint4*>(&Cb[r*136 + c8]);
            *reinterpret_cast<uint4*>((unsigned short*)J.C + (size_t)(row0+r)*J.N + col0 + c8) = v;
        }
    }
}

__launch_bounds__(256)
__global__ void mm2one(MJob a)
{
    __shared__ alignas(16) char smem[MM2_SMEM];
    mm2_body(a, blockIdx.x, smem);
}

__launch_bounds__(256)
__global__ void mm2two(MJob a, MJob b, int asplit)
{
    __shared__ alignas(16) char smem[MM2_SMEM];
    int bid = blockIdx.x;
    if (bid < asplit) mm2_body(a, bid, smem);
    else              mm2_body(b, bid - asplit, smem);
}

// ---------------- fully fused GRU body: BK=32, fragment-order LDS (conflict-free) ----------------
struct GJob {
    const unsigned short *A0, *A1;
    const int *i0, *i1;
    int lda;
    const unsigned short *Wih, *Whh;
    const float *bih, *bhh;
    float *H;
    unsigned short *Hbf, *stateBf;
    const int *sidx;
    int M, nodes;
};

__device__ __forceinline__ void gru_body(const GJob J, int bid, char* smem)
{
    unsigned short* AsB = (unsigned short*)smem;      // 2 x 4096 ushort (16 KB)
    unsigned short* BsB = AsB + 8192;                 // 2 x 12288 ushort (48 KB)
    int tid = threadIdx.x;
    int l = tid & 63, w = tid >> 6;
    int row0 = bid * 128;
    f32x4 acc[24], accN[8];
#pragma unroll
    for (int n=0;n<24;n++) acc[n] = (f32x4){0.f,0.f,0.f,0.f};
#pragma unroll
    for (int n=0;n<8;n++) accN[n] = (f32x4){0.f,0.f,0.f,0.f};

    // fragment-order staging: chunk i holds exactly the 16B lane i reads back.
    // A chunk i = tid: row=(i>>6)*16+(i&15), kslot=(i>>4)&3.
    // B chunk i = q*512+tid: col=(i>>6)*16+(i&15), kslot=(i>>4)&3.
    auto stage = [&](int buf, int st){
        int k0 = st*32;
        unsigned short* As = AsB + buf*4096;
        unsigned short* Bs = BsB + buf*12288;
        {
            int r = (tid >> 6)*16 + (tid & 15);
            int slot = (tid >> 4) & 3;
            const unsigned short* src;
            if (st < 8){
                if (J.i1){
                    if (k0 < 128){ int ri = J.i0 ? J.i0[row0+r] : (row0+r); src = J.A0 + (size_t)ri*128 + k0; }
                    else         { int ri = J.i1[row0+r]; src = J.A1 + (size_t)ri*128 + (k0-128); }
                } else {
                    src = J.A0 + (size_t)(row0+r)*J.lda + k0;
                }
            } else {
                src = J.Hbf + (size_t)(row0+r)*128 + (k0-256);
            }
            gload16((const char*)(src + slot*8), (void*)&As[(size_t)(w*64)*8]);
        }
#pragma unroll
        for (int q=0;q<3;q++){
            int i = q*512 + tid;
            int col = (i >> 6)*16 + (i & 15);
            int slot = (i >> 4) & 3;
            const unsigned short* src = (st < 8) ? (J.Wih + (size_t)col*256 + k0)
                                                 : (J.Whh + (size_t)col*128 + (k0-256));
            gload16((const char*)(src + slot*8), (void*)&Bs[(size_t)(q*512 + w*64)*8]);
        }
    };

    stage(0, 0);
    for (int st=0; st<12; ++st){
        int cur = st & 1;
        if (st+1 < 12){
            stage(cur^1, st+1);
            asm volatile("s_waitcnt vmcnt(4)" ::: "memory");
        } else {
            asm volatile("s_waitcnt vmcnt(0)" ::: "memory");
        }
        __builtin_amdgcn_s_barrier();
        __builtin_amdgcn_sched_barrier(0);
        unsigned short* As = AsB + cur*4096;
        unsigned short* Bs = BsB + cur*12288;
        bf16x8 af = *reinterpret_cast<const bf16x8*>(&As[(size_t)(w*64 + l)*8]);
        if (st < 8){
#pragma unroll
            for (int n=0;n<24;n++){
                bf16x8 bf = *reinterpret_cast<const bf16x8*>(&Bs[(size_t)(n*64 + l)*8]);
                acc[n] = __builtin_amdgcn_mfma_f32_16x16x32_bf16(af, bf, acc[n], 0, 0, 0);
            }
        } else {
#pragma unroll
            for (int n=0;n<24;n++){
                bf16x8 bf = *reinterpret_cast<const bf16x8*>(&Bs[(size_t)(n*64 + l)*8]);
                if (n < 16) acc[n]     = __builtin_amdgcn_mfma_f32_16x16x32_bf16(af, bf, acc[n], 0, 0, 0);
                else        accN[n-16] = __builtin_amdgcn_mfma_f32_16x16x32_bf16(af, bf, accN[n-16], 0, 0, 0);
            }
        }
        __builtin_amdgcn_sched_barrier(0);
        __builtin_amdgcn_s_barrier();
    }

    // ---- two-pass LDS-staged epilogue (64 rows per pass, 51 KB) ----
    __syncthreads();
    float* Hld = (float*)smem;                                  // [64][132] (33792 B)
    unsigned short* Hb = (unsigned short*)(smem + 33792);       // [64][136] (17408 B)
#pragma unroll
    for (int half=0; half<2; ++half){
        int rbase = half*64;
#pragma unroll
        for (int q=0;q<4;q++){
            int idx = tid + q*512;
            int r = idx >> 5, c4 = (idx & 31)*4;
            float4 v = *reinterpret_cast<const float4*>(J.H + (size_t)(row0+rbase+r)*128 + c4);
            *reinterpret_cast<float4*>(&Hld[r*132 + c4]) = v;
        }
        __syncthreads();
        if ((w >> 2) == half){
#pragma unroll
            for (int v=0;v<4;v++){
                int rloc = (w & 3)*16 + (l >> 4)*4 + v;
#pragma unroll
                for (int c=0;c<8;c++){
                    int col = c*16 + (l & 15);
                    float rr = sigf(acc[c][v]    + J.bih[col]     + J.bhh[col]);
                    float zz = sigf(acc[c+8][v]  + J.bih[col+128] + J.bhh[col+128]);
                    float nn = tanhf(acc[c+16][v] + J.bih[col+256] + rr*(accN[c][v] + J.bhh[col+256]));
                    float hv = Hld[rloc*132 + col];
                    float hn = (1.f-zz)*nn + zz*hv;
                    Hld[rloc*132 + col] = hn;
                    Hb[rloc*136 + col] = f2b(hn);
                }
            }
        }
        __syncthreads();
#pragma unroll
        for (int q=0;q<4;q++){
            int idx = tid + q*512;
            int r = idx >> 5, c4 = (idx & 31)*4;
            float4 v = *reinterpret_cast<const float4*>(&Hld[r*132 + c4]);
            *reinterpret_cast<float4*>(J.H + (size_t)(row0+rbase+r)*128 + c4) = v;
        }
#pragma unroll
        for (int q=0;q<2;q++){
            int idx = tid + q*512;
            int r = idx >> 4, c8 = (idx & 15)*8;
            uint4 v = *reinterpret_cast<const uint4*>(&Hb[r*136 + c8]);
            *reinterpret_cast<uint4*>(J.Hbf + (size_t)(row0+rbase+r)*128 + c8) = v;
            int st = clampi(J.sidx[row0+rbase+r],0,J.nodes-1);
            *reinterpret_cast<uint4*>(J.stateBf + (size_t)st*128 + c8) = v;
        }
        __syncthreads();
    }
}

__launch_bounds__(512)
__global__ void gru2(GJob a, GJob b, int asplit)
{
    __shared__ alignas(16) char smem[65536];
    int bid = blockIdx.x;
    if (bid < asplit) gru_body(a, bid, smem);
    else              gru_body(b, bid - asplit, smem);
}

// ---------------- fused GAT attention ----------------
__launch_bounds__(256)
__global__ void k_attn(const unsigned short* __restrict__ SRC, const unsigned short* __restrict__ tgtbf,
                       const float* __restrict__ att, const int* __restrict__ list,
                       const int* __restrict__ offs, const float* __restrict__ batt,
                       unsigned short* __restrict__ msgDbf,
                       float* __restrict__ alphaG, int Dn, int F)
{
    __shared__ float tg[1024];
    __shared__ float alds[128*4];
    __shared__ float accs[4][256];
    int d = blockIdx.x;
    int tid = threadIdx.x;
    int w = tid >> 6, lane = tid & 63;
    for (int u = tid; u < 1024; u += 256) tg[u] = us2f(tgtbf[(size_t)d*1024 + u]);
    __syncthreads();
    int beg = offs[d], end = offs[d+1];
    if (beg < 0) beg = 0; if (end > F) end = F; if (end < beg) end = beg;
    int c0 = w*256 + lane*4;
    float t0 = tg[c0], t1 = tg[c0+1], t2 = tg[c0+2], t3 = tg[c0+3];
    float a0 = att[c0], a1 = att[c0+1], a2 = att[c0+2], a3 = att[c0+3];
    float amax = -3.4e38f;
    for (int i=beg;i<end;i++){
        int f = list[i];
        ushort4 sv = *reinterpret_cast<const ushort4*>(SRC + (size_t)f*1024 + c0);
        float e0 = us2f(sv.x)+t0, e1 = us2f(sv.y)+t1, e2 = us2f(sv.z)+t2, e3 = us2f(sv.w)+t3;
        e0 = e0>0.f?e0:0.2f*e0; e1 = e1>0.f?e1:0.2f*e1;
        e2 = e2>0.f?e2:0.2f*e2; e3 = e3>0.f?e3:0.2f*e3;
        float s = e0*a0 + e1*a1 + e2*a2 + e3*a3;
#pragma unroll
        for (int msk=1; msk<64; msk<<=1) s += __shfl_xor(s, msk);
        int li = i - beg;
        if (li < 128){ if (lane == 0) alds[li*4+w] = s; }
        else         { if (lane == 0) alphaG[(size_t)f*4+w] = s; }
        amax = fmaxf(amax, s);
    }
    __syncthreads();
    float wsum = 0.f;
    for (int i=beg;i<end;i++){
        int li = i - beg;
        float a = (li < 128) ? alds[li*4+w] : alphaG[(size_t)list[i]*4+w];
        wsum += expf(a - amax);
    }
    float iws = 1.f/(wsum + 1e-16f);
    float acc[4] = {0,0,0,0};
    for (int i=beg;i<end;i++){
        int f = list[i];
        int li = i - beg;
        float a = (li < 128) ? alds[li*4+w] : alphaG[(size_t)f*4+w];
        float p = expf(a - amax)*iws;
        ushort4 sv = *reinterpret_cast<const ushort4*>(SRC + (size_t)f*1024 + c0);
        acc[0] += p*us2f(sv.x); acc[1] += p*us2f(sv.y);
        acc[2] += p*us2f(sv.z); acc[3] += p*us2f(sv.w);
    }
#pragma unroll
    for (int j=0;j<4;j++) accs[w][lane*4+j] = acc[j];
    __syncthreads();
    if (tid < 256){
        float m = (accs[0][tid]+accs[1][tid]+accs[2][tid]+accs[3][tid])*0.25f + batt[tid];
        msgDbf[(size_t)d*256 + tid] = f2b(m);
    }
}

// ---------------- fused phiC recurrence: 8 services/block, bf16 gi ----------------
__launch_bounds__(512)
__global__ void k_recur(float* __restrict__ h_srv, const unsigned short* __restrict__ giFb,
                        const unsigned short* __restrict__ Whi,
                        const unsigned short* __restrict__ Wlo,
                        const float* __restrict__ bhh,
                        const int* __restrict__ inv,
                        unsigned short* __restrict__ out_f_bf,
                        int S, int L, int F)
{
    __shared__ float hs[8][129];
    __shared__ alignas(16) unsigned short hsHi[16*128];
    __shared__ alignas(16) unsigned short hsLo[16*128];
    __shared__ float ghs[16][385];
    __shared__ int fLoc[16][8];
    int tid = threadIdx.x;
    int l = tid & 63, w = tid >> 6;
    int lane15 = l & 15, lhi = l >> 4;
    int s0 = blockIdx.x * 8;
    for (int u = tid; u < 2048; u += 512){
        int s=u>>7,k=u&127;
        int ksw = k ^ ((s & 7) << 3);
        if (s < 8){
            float v = h_srv[(size_t)(s0+s)*128+k];
            hs[s][k] = v;
            unsigned short hb = f2b(v);
            hsHi[s*128 + ksw] = hb;
            hsLo[s*128 + ksw] = f2b(v - us2f(hb));
        } else {
            hsHi[s*128 + ksw] = 0;
            hsLo[s*128 + ksw] = 0;
        }
    }
    if (tid < 128) fLoc[tid>>3][tid&7] = inv[(size_t)(s0+(tid&7))*L + (tid>>3)];
    bf16x8 wHi[3][4], wLo[3][4];
#pragma unroll
    for (int ct=0; ct<3; ++ct){
        int col = w*48 + ct*16 + lane15;
#pragma unroll
        for (int ks=0; ks<4; ++ks){
            size_t off = (size_t)col*128 + ks*32 + lhi*8;
            wHi[ct][ks] = *reinterpret_cast<const bf16x8*>(Whi + off);
            wLo[ct][ks] = *reinterpret_cast<const bf16x8*>(Wlo + off);
        }
    }
    __syncthreads();
    for (int t=0;t<L;++t){
        bf16x8 hHi[4], hLo[4];
#pragma unroll
        for (int ks=0; ks<4; ++ks){
            int ek = ks*32 + lhi*8;
            int off = lane15*128 + (ek ^ ((lane15 & 7) << 3));
            hHi[ks] = *reinterpret_cast<const bf16x8*>(&hsHi[off]);
            hLo[ks] = *reinterpret_cast<const bf16x8*>(&hsLo[off]);
        }
#pragma unroll
        for (int ct=0; ct<3; ++ct){
            f32x4 acc = (f32x4){0.f,0.f,0.f,0.f};
#pragma unroll
            for (int ks=0; ks<4; ++ks){
                acc = __builtin_amdgcn_mfma_f32_16x16x32_bf16(hHi[ks], wHi[ct][ks], acc, 0,0,0);
                acc = __builtin_amdgcn_mfma_f32_16x16x32_bf16(hLo[ks], wHi[ct][ks], acc, 0,0,0);
                acc = __builtin_amdgcn_mfma_f32_16x16x32_bf16(hHi[ks], wLo[ct][ks], acc, 0,0,0);
            }
            int col = w*48 + ct*16 + lane15;
            float bb = bhh[col];
#pragma unroll
            for (int v=0; v<4; ++v){
                ghs[lhi*4 + v][col] = acc[v] + bb;
            }
        }
        __syncthreads();
        for (int u = tid; u < 1024; u += 512){
            int s=u>>7, k=u&127; int f = fLoc[t][s];
            if (f >= 0 && f < F){
                const unsigned short* gp = giFb + (size_t)f*384;
                float r  = sigf(us2f(gp[k])     + ghs[s][k]);
                float zz = sigf(us2f(gp[128+k]) + ghs[s][128+k]);
                float n  = tanhf(us2f(gp[256+k]) + r*ghs[s][256+k]);
                float hn = (1.f-zz)*n + zz*hs[s][k];
                hs[s][k] = hn;
                unsigned short hb = f2b(hn);
                int ksw = k ^ ((s & 7) << 3);
                hsHi[s*128 + ksw] = hb;
                hsLo[s*128 + ksw] = f2b(hn - us2f(hb));
                out_f_bf[(size_t)f*128+k] = hb;
            }
        }
        __syncthreads();
    }
    for (int u = tid; u < 1024; u += 512){ int s=u>>7,k=u&127; h_srv[(size_t)(s0+s)*128+k] = hs[s][k]; }
}

__global__ void k_count(const int* __restrict__ row, int* __restrict__ counts, int F, int Dn)
{ int f = blockIdx.x*blockDim.x + threadIdx.x; if (f < F) atomicAdd(&counts[clampi(row[f],0,Dn-1)], 1); }

__global__ void k_scan(const int* __restrict__ counts, int* __restrict__ offs, int D)
{
    __shared__ int part[257];
    int tid = threadIdx.x;
    int per = (D + 255) / 256;
    int s = 0;
    for (int i=0;i<per;i++){ int idx = tid*per+i; if (idx < D) s += counts[idx]; }
    part[tid] = s;
    __syncthreads();
    if (tid == 0){
        int acc = 0;
        for (int i=0;i<256;i++){ int v = part[i]; part[i] = acc; acc += v; }
        part[256] = acc;
    }
    __syncthreads();
    int acc = part[tid];
    for (int i=0;i<per;i++){ int idx = tid*per+i; if (idx < D){ offs[idx] = acc; acc += counts[idx]; } }
    if (tid == 0) offs[D] = part[256];
}

__global__ void k_fill(const int* __restrict__ row, const int* __restrict__ offs,
                       int* __restrict__ cursor, int* __restrict__ list, int F, int Dn)
{
    int f = blockIdx.x*blockDim.x + threadIdx.x;
    if (f >= F) return;
    int r = clampi(row[f],0,Dn-1);
    int p = atomicAdd(&cursor[r], 1);
    int pos = offs[r]+p;
    if (pos >= 0 && pos < F) list[pos] = f;
}

__global__ void k_build_inv(const int* __restrict__ fs, const int* __restrict__ fp,
                            int* __restrict__ inv, int F, int L, int S)
{
    int f = blockIdx.x*blockDim.x + threadIdx.x;
    if (f >= F) return;
    inv[clampi(fs[f],0,S-1)*L + clampi(fp[f],0,L-1)] = f;
}

__global__ void k_pool_add(const float* __restrict__ frag, const int* __restrict__ fs,
                           float* __restrict__ pooled, int F, int S)
{
    int t = blockIdx.x*blockDim.x + threadIdx.x;
    int i = t >> 7, j = t & 127;
    if (i >= F) return;
    atomicAdd(&pooled[(size_t)clampi(fs[i],0,S-1)*128 + j], frag[(size_t)i*128 + j]);
}

__global__ void k_pool_div(float* __restrict__ pooled, const int* __restrict__ lengths, int S)
{
    int t = blockIdx.x*blockDim.x + threadIdx.x;
    int i = t >> 7, j = t & 127;
    if (i >= S) return;
    int l = lengths[i]; if (l < 1) l = 1;
    pooled[(size_t)i*128 + j] /= (float)l;
}

__global__ void k_dot_out(const float* __restrict__ H, const float* __restrict__ W3,
                          const float* __restrict__ b3, float* __restrict__ outv, int off)
{
    __shared__ float red[256];
    int s = blockIdx.x, tid = threadIdx.x;
    red[tid] = H[(size_t)s*256 + tid] * W3[tid];
    __syncthreads();
    for (int st=128; st; st>>=1){ if (tid < st) red[tid] += red[tid+st]; __syncthreads(); }
    if (tid == 0) outv[off + s] = red[0] + b3[0];
}

// =====================================================================================
extern "C" void kernel_launch(void* const* d_in, const int* in_sizes, int n_in,
                              void* d_out, int out_size, void* d_ws, size_t ws_size,
                              hipStream_t stream)
{
    (void)n_in; (void)out_size; (void)ws_size;
    const float* realnode = (const float*)d_in[0];
    const float* arr      = (const float*)d_in[1];
    const int* r_exe   = (const int*)d_in[2];
    const int* r_idev  = (const int*)d_in[3];
    const int* r_ifrag = (const int*)d_in[4];
    const int* r_fdn   = (const int*)d_in[5];
    const int* r_fdr   = (const int*)d_in[6];
    const int* r_len   = (const int*)d_in[7];
    const int* r_fsvc  = (const int*)d_in[8];
    const int* r_fpos  = (const int*)d_in[9];
    const float *W_dev=(const float*)d_in[10], *b_dev=(const float*)d_in[11];
    const float *W_frg=(const float*)d_in[12], *b_frg=(const float*)d_in[13];
    const float *W_srv=(const float*)d_in[14], *b_srv=(const float*)d_in[15];
    const float *C_Wih=(const float*)d_in[16], *C_Whh=(const float*)d_in[17], *C_bih=(const float*)d_in[18], *C_bhh=(const float*)d_in[19];
    const float *F_Wih=(const float*)d_in[20], *F_Whh=(const float*)d_in[21], *F_bih=(const float*)d_in[22], *F_bhh=(const float*)d_in[23];
    const float *D_Wih=(const float*)d_in[24], *D_Whh=(const float*)d_in[25], *D_bih=(const float*)d_in[26], *D_bhh=(const float*)d_in[27];
    const float *W_src=(const float*)d_in[28], *b_src=(const float*)d_in[29];
    const float *W_tgt=(const float*)d_in[30], *b_tgt=(const float*)d_in[31];
    const float *att=(const float*)d_in[32], *bias_att=(const float*)d_in[33];
    const float *Wt1=(const float*)d_in[34], *bt1=(const float*)d_in[35], *Wt2=(const float*)d_in[36], *bt2=(const float*)d_in[37], *Wt3=(const float*)d_in[38], *bt3=(const float*)d_in[39];
    const float *Wl1=(const float*)d_in[40], *bl1=(const float*)d_in[41], *Wl2=(const float*)d_in[42], *bl2=(const float*)d_in[43], *Wl3=(const float*)d_in[44], *bl3=(const float*)d_in[45];
    float* outp = (float*)d_out;

    const int S  = in_sizes[7];
    const int Dn = in_sizes[3];
    const int F  = in_sizes[4];
    const int L  = in_sizes[2] / (2*S);
    const int nreal = in_sizes[0]/5;
    const int nodes = nreal + 1;
    const int NIT = 3;

    char* wp = (char*)d_ws;
    auto alloc = [&](size_t nelem)->float*{
        float* p = (float*)wp;
        wp += ((nelem*4 + 255)/256)*256;
        return p;
    };
    float* h_srv  = alloc((size_t)S*128);
    float* fragA  = alloc((size_t)F*128);
    float* devA   = alloc((size_t)Dn*128);
    float* alphaB = alloc((size_t)F*4);
    float* UNION  = alloc((size_t)F*512);
    unsigned short* giFb = (unsigned short*)UNION;
    unsigned short* SRC  = (unsigned short*)UNION;
    float* Z      = alloc((size_t)Dn*1024);
    float* TGTf   = alloc((size_t)Dn*512);
    unsigned short* TGT = (unsigned short*)TGTf;
    float* pooled = alloc((size_t)S*128);
    unsigned short* state_bf = (unsigned short*)alloc((size_t)nodes*64);
    unsigned short* out_f_bf = (unsigned short*)alloc((size_t)F*64);
    unsigned short* fragA_bf = (unsigned short*)alloc((size_t)F*64);
    unsigned short* devA_bf  = (unsigned short*)alloc((size_t)Dn*64);
    unsigned short* msgD_bf  = (unsigned short*)alloc((size_t)Dn*128);
    unsigned short* tCWih   = (unsigned short*)alloc(384*256/2);
    unsigned short* tCWhhHi = (unsigned short*)alloc(384*128/2);
    unsigned short* tCWhhLo = (unsigned short*)alloc(384*128/2);
    unsigned short* tFWih   = (unsigned short*)alloc(384*256/2);
    unsigned short* tFWhh   = (unsigned short*)alloc(384*128/2);
    unsigned short* tDWih   = (unsigned short*)alloc(384*256/2);
    unsigned short* tDWhh   = (unsigned short*)alloc(384*128/2);
    unsigned short* tWtgt   = (unsigned short*)alloc(1024*128/2);
    unsigned short* tWsrc   = (unsigned short*)alloc(1024*256/2);
    int* cExe   = (int*)alloc((size_t)S*2*L);
    int* cIdev  = (int*)alloc((size_t)Dn);
    int* cIfrag = (int*)alloc((size_t)F);
    int* cFdn   = (int*)alloc((size_t)F);
    int* cFdr   = (int*)alloc((size_t)F);
    int* cLen   = (int*)alloc((size_t)S);
    int* cFsvc  = (int*)alloc((size_t)F);
    int* cFpos  = (int*)alloc((size_t)F);
    int* inv    = (int*)alloc((size_t)S*L);
    int* counts = (int*)alloc((size_t)Dn);
    int* offs   = (int*)alloc((size_t)Dn+1);
    int* cursor = (int*)alloc((size_t)Dn);
    int* list   = (int*)alloc((size_t)F);

    const int* det = r_idev;
    auto cvt = [&](const int* src, int* dst, int n){
        k_cvt<<<dim3((n+255)/256),256,0,stream>>>(src, dst, n, det);
    };
    cvt(r_exe,  cExe,  S*2*L);
    cvt(r_idev, cIdev, Dn);
    cvt(r_ifrag,cIfrag,F);
    cvt(r_fdn,  cFdn,  F);
    cvt(r_fdr,  cFdr,  F);
    cvt(r_len,  cLen,  S);
    cvt(r_fsvc, cFsvc, F);
    cvt(r_fpos, cFpos, F);

    k_wt<<<dim3((98304+255)/256),256,0,stream>>>(C_Wih, tCWih, 384, 8, 255, 98304);
    k_wt2<<<dim3((49152+255)/256),256,0,stream>>>(C_Whh, tCWhhHi, tCWhhLo, 384, 7, 127, 49152);
    k_wt<<<dim3((98304+255)/256),256,0,stream>>>(F_Wih, tFWih, 384, 8, 255, 98304);
    k_wt<<<dim3((49152+255)/256),256,0,stream>>>(F_Whh, tFWhh, 384, 7, 127, 49152);
    k_wt<<<dim3((98304+255)/256),256,0,stream>>>(D_Wih, tDWih, 384, 8, 255, 98304);
    k_wt<<<dim3((49152+255)/256),256,0,stream>>>(D_Whh, tDWhh, 384, 7, 127, 49152);
    k_wt<<<dim3((131072+255)/256),256,0,stream>>>(W_tgt, tWtgt, 1024, 7, 127, 131072);
    k_wt<<<dim3((262144+255)/256),256,0,stream>>>(W_src, tWsrc, 1024, 8, 255, 262144);

    hipMemsetAsync(state_bf, 0, (size_t)nodes*128*2, stream);
    hipMemsetAsync(inv, 0xFF, (size_t)S*L*4, stream);
    hipMemsetAsync(counts, 0, (size_t)Dn*4, stream);
    hipMemsetAsync(cursor, 0, (size_t)Dn*4, stream);

    k_proj5<<<dim3((Dn*128+255)/256),256,0,stream>>>(realnode, W_dev, b_dev, cIdev, cIdev,
        nullptr, state_bf, devA, devA_bf, Dn, nreal, nodes);
    k_proj5<<<dim3(((size_t)F*128+255)/256),256,0,stream>>>(realnode, W_frg, b_frg, cIfrag, cIfrag,
        nullptr, state_bf, fragA, fragA_bf, F, nreal, nodes);
    k_proj5<<<dim3((S*128+255)/256),256,0,stream>>>(arr, W_srv, b_srv, nullptr, nullptr,
        h_srv, nullptr, nullptr, nullptr, S, S, nodes);
    k_build_inv<<<dim3((F+255)/256),256,0,stream>>>(cFsvc, cFpos, inv, F, L, S);
    k_count<<<dim3((F+255)/256),256,0,stream>>>(cFdr, counts, F, Dn);
    k_scan<<<1,256,0,stream>>>(counts, offs, Dn);
    k_fill<<<dim3((F+255)/256),256,0,stream>>>(cFdr, offs, cursor, list, F, Dn);

    const int nrF = F/128, nrD = Dn/128;
    MJob jGi  = { state_bf, state_bf, cIfrag, cFdn, tCWih, C_bih, giFb, 384, 256, 2, nrF, 1.f };
    MJob jTgt = { devA_bf, devA_bf, nullptr, nullptr, tWtgt, b_tgt, TGT, 1024, 128, 2, nrD, 1.f };
    MJob jSrc = { out_f_bf, fragA_bf, nullptr, nullptr, tWsrc, b_src, SRC, 1024, 256, 2, nrF, 1.f };
    GJob jF = { out_f_bf, state_bf, nullptr, cFdn, 128, tFWih, tFWhh, F_bih, F_bhh,
                fragA, fragA_bf, state_bf, cIfrag, F, nodes };
    GJob jD = { msgD_bf, nullptr, nullptr, nullptr, 256, tDWih, tDWhh, D_bih, D_bhh,
                devA, devA_bf, state_bf, cIdev, Dn, nodes };

    for (int it=0; it<NIT; ++it){
        mm2two<<<dim3(3*nrF + 8*nrD),256,0,stream>>>(jGi, jTgt, 3*nrF);
        k_recur<<<dim3(S/8),512,0,stream>>>(h_srv, giFb, tCWhhHi, tCWhhLo, C_bhh, inv,
            out_f_bf, S, L, F);
        mm2one<<<dim3(8*nrF),256,0,stream>>>(jSrc);
        k_attn<<<dim3(Dn),256,0,stream>>>(SRC, TGT, att, list, offs, bias_att,
            msgD_bf, alphaB, Dn, F);
        gru2<<<dim3(nrF + nrD),512,0,stream>>>(jF, jD, nrF);
    }

    // readout
    hipMemsetAsync(pooled, 0, (size_t)S*128*4, stream);
    k_pool_add<<<dim3(((size_t)F*128+255)/256),256,0,stream>>>(fragA, cFsvc, pooled, F, S);
    k_pool_div<<<dim3((S*128+255)/256),256,0,stream>>>(pooled, cLen, S);
    float* h1 = (float*)TGTf;
    k_mm<<<dim3(256/128, S/128),256,0,stream>>>(pooled, 128, Wl1, 256, bl1, h1, S, 256, 128, 1, 1.f, 0);
    k_mm<<<dim3(256/128, S/128),256,0,stream>>>(h1, 256, Wl2, 256, bl2, Z, S, 256, 256, 1, 1.f, 0);
    k_dot_out<<<dim3(S),256,0,stream>>>(Z, Wl3, bl3, outp, 0);
    k_mm<<<dim3(256/128, S/128),256,0,stream>>>(h_srv, 128, Wt1, 256, bt1, h1, S, 256, 128, 1, 1.f, 0);
    k_mm<<<dim3(256/128, S/128),256,0,stream>>>(h1, 256, Wt2, 256, bt2, Z, S, 256, 256, 1, 1.f, 0);
    k_dot_out<<<dim3(S),256,0,stream>>>(Z, Wt3, bt3, outp, S);
}

// Round 19
// 804.954 us; speedup vs baseline: 1.1457x; 1.1457x over previous
//
#include <hip/hip_runtime.h>
#include <hip/hip_bf16.h>

typedef __attribute__((ext_vector_type(8))) short bf16x8;
typedef __attribute__((ext_vector_type(4))) float f32x4;

__device__ __forceinline__ float sigf(float x){ return 1.0f/(1.0f+expf(-x)); }
__device__ __forceinline__ int clampi(int v, int lo, int hi){ return v<lo?lo:(v>hi?hi:v); }
__device__ __forceinline__ unsigned short f2b(float f){
    __hip_bfloat16 h = __float2bfloat16(f);
    return *reinterpret_cast<unsigned short*>(&h);
}
__device__ __forceinline__ float us2f(unsigned short u){ return __uint_as_float(((unsigned)u)<<16); }

__device__ __forceinline__ void gload16(const void* g, void* l){
    __builtin_amdgcn_global_load_lds((const __attribute__((address_space(1))) void*)g,
                                     (__attribute__((address_space(3))) void*)l, 16, 0, 0);
}

// ---- int64/int32 tolerant index conversion ----
__global__ void k_cvt(const int* __restrict__ src, int* __restrict__ dst, int n,
                      const int* __restrict__ det)
{
    int i = blockIdx.x*blockDim.x + threadIdx.x;
    if (i >= n) return;
    int stride = (det[1] == 0) ? 2 : 1;
    dst[i] = src[(size_t)i*stride];
}

__global__ void k_wt(const float* __restrict__ W, unsigned short* __restrict__ Wt,
                     int N, int kshift, int kmask, int total)
{
    int idx = blockIdx.x*blockDim.x + threadIdx.x;
    if (idx >= total) return;
    int n = idx >> kshift, k = idx & kmask;
    Wt[idx] = f2b(W[(size_t)k*N + n]);
}

__global__ void k_wt2(const float* __restrict__ W, unsigned short* __restrict__ Whi,
                      unsigned short* __restrict__ Wlo, int N, int kshift, int kmask, int total)
{
    int idx = blockIdx.x*blockDim.x + threadIdx.x;
    if (idx >= total) return;
    int n = idx >> kshift, k = idx & kmask;
    float v = W[(size_t)k*N + n];
    unsigned short hi = f2b(v);
    Whi[idx] = hi;
    Wlo[idx] = f2b(v - us2f(hi));
}

// ---------------- init projections ----------------
__global__ void k_proj5(const float* __restrict__ X, const float* __restrict__ W,
                        const float* __restrict__ bias,
                        const int* __restrict__ gidx, const int* __restrict__ sidx,
                        float* __restrict__ out, unsigned short* __restrict__ outBf,
                        float* __restrict__ out2, unsigned short* __restrict__ out2Bf,
                        int M, int nrows, int nodes)
{
    int t = blockIdx.x*blockDim.x + threadIdx.x;
    int i = t >> 7, j = t & 127;
    if (i >= M) return;
    int src = gidx ? clampi(gidx[i]-1, 0, nrows-1) : i;
    const float* xp = X + (size_t)src*5;
    float acc = bias[j];
#pragma unroll
    for (int k=0;k<5;k++) acc += xp[k] * W[k*128+j];
    int dr = sidx ? clampi(sidx[i], 0, nodes-1) : i;
    if (out)   out[(size_t)dr*128 + j] = acc;
    if (outBf) outBf[(size_t)dr*128 + j] = f2b(acc);
    if (out2)  out2[(size_t)i*128 + j] = acc;
    if (out2Bf) out2Bf[(size_t)i*128 + j] = f2b(acc);
}

// ---------------- f32 tiled GEMM (readout heads only) ----------------
__launch_bounds__(256)
__global__ void k_mm(const float* __restrict__ A0, int lda,
                     const float* __restrict__ B, int ldb,
                     const float* __restrict__ bias, float* __restrict__ C,
                     int M, int N, int K, int relu, float scale, int accum)
{
    __shared__ float As[16][132];
    __shared__ float Bs[16][132];
    int tid = threadIdx.x;
    int tx = tid & 15, ty = tid >> 4;
    int row0 = blockIdx.y * 128, col0 = blockIdx.x * 128;
    float acc[8][8] = {};
    for (int k0 = 0; k0 < K; k0 += 16){
#pragma unroll
        for (int q = 0; q < 2; ++q){
            int idx = tid + q*256;
            int r = idx >> 2, k4 = (idx & 3) * 4;
            const float* src = A0 + (size_t)(row0+r)*lda + k0 + k4;
            float4 v = *reinterpret_cast<const float4*>(src);
            As[k4+0][r]=v.x; As[k4+1][r]=v.y; As[k4+2][r]=v.z; As[k4+3][r]=v.w;
        }
#pragma unroll
        for (int q = 0; q < 2; ++q){
            int idx = tid + q*256;
            int kb = idx >> 5, n4 = (idx & 31) * 4;
            float4 v = *reinterpret_cast<const float4*>(B + (size_t)(k0+kb)*ldb + col0 + n4);
            *reinterpret_cast<float4*>(&Bs[kb][n4]) = v;
        }
        __syncthreads();
#pragma unroll
        for (int k = 0; k < 16; ++k){
            float a[8], b[8];
            *(float4*)&a[0] = *(const float4*)&As[k][ty*8];
            *(float4*)&a[4] = *(const float4*)&As[k][ty*8+4];
            *(float4*)&b[0] = *(const float4*)&Bs[k][tx*8];
            *(float4*)&b[4] = *(const float4*)&Bs[k][tx*8+4];
#pragma unroll
            for (int i=0;i<8;i++)
#pragma unroll
                for (int j=0;j<8;j++) acc[i][j] += a[i]*b[j];
        }
        __syncthreads();
    }
    float bb[8];
#pragma unroll
    for (int j=0;j<8;j++) bb[j] = bias ? bias[col0+tx*8+j] : 0.f;
#pragma unroll
    for (int i=0;i<8;i++){
        float* cp = C + (size_t)(row0+ty*8+i)*N + col0 + tx*8;
#pragma unroll
        for (int jq=0;jq<2;jq++){
            float4 prev = accum ? *(const float4*)(cp+jq*4) : make_float4(0,0,0,0);
            float o[4];
#pragma unroll
            for (int c=0;c<4;c++){
                float u = acc[i][jq*4+c] + bb[jq*4+c];
                if (relu) u = fmaxf(u,0.f);
                o[c] = (&prev.x)[c] + scale*u;
            }
            *(float4*)(cp+jq*4) = make_float4(o[0],o[1],o[2],o[3]);
        }
    }
}

// ---------------- pipelined bf16 MFMA GEMM body (counted vmcnt, 2-barrier) ----------------
struct MJob {
    const unsigned short *A0, *A1;
    const int *i0, *i1;
    const unsigned short *Wt;
    const float *bias;
    void *C;
    int N, K, epi, nrow;
    float scale;
};

#define MM2_SMEM 67840

__device__ __forceinline__ void mm2_body(const MJob J, int bid, char* smem)
{
    unsigned short* AsB = (unsigned short*)smem;
    unsigned short* BsB = AsB + 16384;
    int tid = threadIdx.x;
    int l = tid & 63, w = tid >> 6;
    int wr = w >> 1, wc = w & 1;
    int row0 = (bid % J.nrow) * 128, col0 = (bid / J.nrow) * 128;
    int nK = J.K >> 6;

    f32x4 acc[4][4];
#pragma unroll
    for (int m=0;m<4;m++)
#pragma unroll
        for (int n=0;n<4;n++) acc[m][n] = (f32x4){0.f,0.f,0.f,0.f};

    auto stage = [&](int buf, int k0){
        unsigned short* As = AsB + buf*8192;
        unsigned short* Bs = BsB + buf*8192;
#pragma unroll
        for (int q=0;q<4;q++){
            int slot = q*256 + w*64 + l;
            int r = slot >> 3, c8 = slot & 7;
            int g8 = c8 ^ (r & 7);
            int row; const unsigned short* base; int kl;
            if (k0 < 128){ row = J.i0 ? J.i0[row0+r] : (row0+r); base = J.A0; kl = k0; }
            else         { row = J.i1 ? J.i1[row0+r] : (row0+r); base = J.A1; kl = k0-128; }
            const char* g = (const char*)(base + (size_t)row*128 + kl) + g8*16;
            gload16(g, (void*)&As[(size_t)(q*256 + w*64)*8]);
        }
#pragma unroll
        for (int q=0;q<4;q++){
            int slot = q*256 + w*64 + l;
            int n = slot >> 3, kc = slot & 7;
            int g8 = kc ^ (n & 7);
            const char* g = (const char*)(J.Wt + (size_t)(col0+n)*J.K + k0) + g8*16;
            gload16(g, (void*)&Bs[(size_t)(q*256 + w*64)*8]);
        }
    };

    stage(0, 0);
    for (int ks=0; ks<nK; ++ks){
        int cur = ks & 1;
        if (ks+1 < nK){
            stage(cur^1, (ks+1)*64);
            asm volatile("s_waitcnt vmcnt(8)" ::: "memory");
        } else {
            asm volatile("s_waitcnt vmcnt(0)" ::: "memory");
        }
        __builtin_amdgcn_s_barrier();
        __builtin_amdgcn_sched_barrier(0);
        unsigned short* As = AsB + cur*8192;
        unsigned short* Bs = BsB + cur*8192;
#pragma unroll
        for (int kk = 0; kk < 2; ++kk){
            int ek = kk*32 + (l >> 4) * 8;
            bf16x8 af[4], bf[4];
#pragma unroll
            for (int m=0;m<4;m++){
                int r = wr*64 + m*16 + (l & 15);
                af[m] = *reinterpret_cast<const bf16x8*>(&As[r*64 + (ek ^ ((r & 7) << 3))]);
            }
#pragma unroll
            for (int n=0;n<4;n++){
                int c = wc*64 + n*16 + (l & 15);
                bf[n] = *reinterpret_cast<const bf16x8*>(&Bs[c*64 + (ek ^ ((c & 7) << 3))]);
            }
#pragma unroll
            for (int m=0;m<4;m++)
#pragma unroll
                for (int n=0;n<4;n++)
                    acc[m][n] = __builtin_amdgcn_mfma_f32_16x16x32_bf16(af[m], bf[n], acc[m][n], 0, 0, 0);
        }
        __builtin_amdgcn_sched_barrier(0);
        __builtin_amdgcn_s_barrier();
    }

    if (J.epi == 0){
        float* Ct = (float*)smem;
#pragma unroll
        for (int m=0;m<4;m++){
#pragma unroll
            for (int v=0;v<4;v++){
                int rl = wr*64 + m*16 + (l >> 4)*4 + v;
#pragma unroll
                for (int n=0;n<4;n++){
                    int c = wc*64 + n*16 + (l & 15);
                    Ct[rl*132 + c] = J.scale*acc[m][n][v] + (J.bias ? J.bias[col0+c] : 0.f);
                }
            }
        }
        __syncthreads();
#pragma unroll
        for (int q=0;q<16;q++){
            int idx = tid + q*256;
            int r = idx >> 5, c4 = (idx & 31)*4;
            float4 v = *reinterpret_cast<const float4*>(&Ct[r*132 + c4]);
            *reinterpret_cast<float4*>((float*)J.C + (size_t)(row0+r)*J.N + col0 + c4) = v;
        }
    } else {
        unsigned short* Cb = (unsigned short*)smem;
#pragma unroll
        for (int m=0;m<4;m++){
#pragma unroll
            for (int v=0;v<4;v++){
                int rl = wr*64 + m*16 + (l >> 4)*4 + v;
#pragma unroll
                for (int n=0;n<4;n++){
                    int c = wc*64 + n*16 + (l & 15);
                    Cb[rl*136 + c] = f2b(J.scale*acc[m][n][v] + (J.bias ? J.bias[col0+c] : 0.f));
                }
            }
        }
        __syncthreads();
#pragma unroll
        for (int q=0;q<8;q++){
            int idx = tid + q*256;
            int r = idx >> 4, c8 = (idx & 15)*8;
            uint4 v = *reinterpret_cast<const uint4*>(&Cb[r*136 + c8]);
            *reinterpret_cast<uint4*>((unsigned short*)J.C + (size_t)(row0+r)*J.N + col0 + c8) = v;
        }
    }
}

__launch_bounds__(256)
__global__ void mm2one(MJob a)
{
    __shared__ alignas(16) char smem[MM2_SMEM];
    mm2_body(a, blockIdx.x, smem);
}

__launch_bounds__(256)
__global__ void mm2two(MJob a, MJob b, int asplit)
{
    __shared__ alignas(16) char smem[MM2_SMEM];
    int bid = blockIdx.x;
    if (bid < asplit) mm2_body(a, bid, smem);
    else              mm2_body(b, bid - asplit, smem);
}

// ---------------- fully fused GRU body: BK=64, fragment-order LDS, bf16-only H ----------------
struct GJob {
    const unsigned short *A0, *A1;
    const int *i0, *i1;
    int lda;
    const unsigned short *Wih, *Whh;
    const float *bih, *bhh;
    unsigned short *Hbf, *stateBf;
    const int *sidx;
    int M, nodes;
};

__device__ __forceinline__ void gru_body(const GJob J, int bid, char* smem)
{
    unsigned short* AsB = (unsigned short*)smem;      // 2 x 8192 ushort (32 KB)
    unsigned short* BsB = AsB + 2*8192;               // 2 x 24576 ushort (96 KB)
    int tid = threadIdx.x;
    int l = tid & 63, w = tid >> 6;
    int row0 = bid * 128;
    f32x4 acc[24], accN[8];
#pragma unroll
    for (int n=0;n<24;n++) acc[n] = (f32x4){0.f,0.f,0.f,0.f};
#pragma unroll
    for (int n=0;n<8;n++) accN[n] = (f32x4){0.f,0.f,0.f,0.f};

    // fragment-order staging (conflict-free): stage st in [0,6): gi K=256 (0..3), gh K=128 (4..5)
    // A frag (kk,wv): lane reads row=wv*16+(lane&15), k=k0+kk*32+(lane>>4)*8
    // B frag (kk,n):  lane reads col=n*16+(lane&15),  k=k0+kk*32+(lane>>4)*8
    auto stage = [&](int buf, int st){
        int k0 = st*64;
        unsigned short* As = AsB + buf*8192;
        unsigned short* Bs = BsB + buf*24576;
#pragma unroll
        for (int q=0;q<2;q++){
            int i = q*512 + tid;
            int frag = i >> 6, lane = i & 63;
            int kk = frag >> 3, wv = frag & 7;
            int r = wv*16 + (lane & 15);
            int slot = kk*4 + ((lane >> 4) & 3);
            const unsigned short* src;
            if (st < 4){
                if (J.i1){
                    if (k0 < 128){ int ri = J.i0 ? J.i0[row0+r] : (row0+r); src = J.A0 + (size_t)ri*128 + k0; }
                    else         { int ri = J.i1[row0+r]; src = J.A1 + (size_t)ri*128 + (k0-128); }
                } else {
                    src = J.A0 + (size_t)(row0+r)*J.lda + k0;
                }
            } else {
                src = J.Hbf + (size_t)(row0+r)*128 + (k0-256);
            }
            gload16((const char*)(src + slot*8), (void*)&As[(size_t)(q*512 + w*64)*8]);
        }
#pragma unroll
        for (int q=0;q<6;q++){
            int i = q*512 + tid;
            int frag = i >> 6, lane = i & 63;
            int kk = frag / 24, n = frag % 24;
            int col = n*16 + (lane & 15);
            int slot = kk*4 + ((lane >> 4) & 3);
            const unsigned short* src = (st < 4) ? (J.Wih + (size_t)col*256 + k0)
                                                 : (J.Whh + (size_t)col*128 + (k0-256));
            gload16((const char*)(src + slot*8), (void*)&Bs[(size_t)(q*512 + w*64)*8]);
        }
    };

    stage(0, 0);
    for (int st=0; st<6; ++st){
        int cur = st & 1;
        if (st+1 < 6){
            stage(cur^1, st+1);
            asm volatile("s_waitcnt vmcnt(8)" ::: "memory");
        } else {
            asm volatile("s_waitcnt vmcnt(0)" ::: "memory");
        }
        __builtin_amdgcn_s_barrier();
        __builtin_amdgcn_sched_barrier(0);
        unsigned short* As = AsB + cur*8192;
        unsigned short* Bs = BsB + cur*24576;
        if (st < 4){
#pragma unroll
            for (int kk=0; kk<2; ++kk){
                bf16x8 af = *reinterpret_cast<const bf16x8*>(&As[(size_t)((kk*8 + w)*64 + l)*8]);
#pragma unroll
                for (int n=0;n<24;n++){
                    bf16x8 bf = *reinterpret_cast<const bf16x8*>(&Bs[(size_t)((kk*24 + n)*64 + l)*8]);
                    acc[n] = __builtin_amdgcn_mfma_f32_16x16x32_bf16(af, bf, acc[n], 0, 0, 0);
                }
            }
        } else {
#pragma unroll
            for (int kk=0; kk<2; ++kk){
                bf16x8 af = *reinterpret_cast<const bf16x8*>(&As[(size_t)((kk*8 + w)*64 + l)*8]);
#pragma unroll
                for (int n=0;n<24;n++){
                    bf16x8 bf = *reinterpret_cast<const bf16x8*>(&Bs[(size_t)((kk*24 + n)*64 + l)*8]);
                    if (n < 16) acc[n]     = __builtin_amdgcn_mfma_f32_16x16x32_bf16(af, bf, acc[n], 0, 0, 0);
                    else        accN[n-16] = __builtin_amdgcn_mfma_f32_16x16x32_bf16(af, bf, accN[n-16], 0, 0, 0);
                }
            }
        }
        __builtin_amdgcn_sched_barrier(0);
        __builtin_amdgcn_s_barrier();
    }

    // ---- bf16-only epilogue: coalesced Hbf load -> pointwise -> coalesced stores ----
    __syncthreads();
    unsigned short* Hb = (unsigned short*)smem;   // [128][136] bf16 (34816 B)
#pragma unroll
    for (int q=0;q<4;q++){
        int idx = tid + q*512;
        int r = idx >> 4, c8 = (idx & 15)*8;
        uint4 v = *reinterpret_cast<const uint4*>(J.Hbf + (size_t)(row0+r)*128 + c8);
        *reinterpret_cast<uint4*>(&Hb[r*136 + c8]) = v;
    }
    __syncthreads();
#pragma unroll
    for (int v=0;v<4;v++){
        int rloc = w*16 + (l >> 4)*4 + v;
#pragma unroll
        for (int c=0;c<8;c++){
            int col = c*16 + (l & 15);
            float rr = sigf(acc[c][v]    + J.bih[col]     + J.bhh[col]);
            float zz = sigf(acc[c+8][v]  + J.bih[col+128] + J.bhh[col+128]);
            float nn = tanhf(acc[c+16][v] + J.bih[col+256] + rr*(accN[c][v] + J.bhh[col+256]));
            float hv = us2f(Hb[rloc*136 + col]);
            float hn = (1.f-zz)*nn + zz*hv;
            Hb[rloc*136 + col] = f2b(hn);
        }
    }
    __syncthreads();
#pragma unroll
    for (int q=0;q<4;q++){
        int idx = tid + q*512;
        int r = idx >> 4, c8 = (idx & 15)*8;
        uint4 v = *reinterpret_cast<const uint4*>(&Hb[r*136 + c8]);
        *reinterpret_cast<uint4*>(J.Hbf + (size_t)(row0+r)*128 + c8) = v;
        int st = clampi(J.sidx[row0+r],0,J.nodes-1);
        *reinterpret_cast<uint4*>(J.stateBf + (size_t)st*128 + c8) = v;
    }
}

__launch_bounds__(512)
__global__ void gru2(GJob a, GJob b, int asplit)
{
    __shared__ alignas(16) char smem[131072];
    int bid = blockIdx.x;
    if (bid < asplit) gru_body(a, bid, smem);
    else              gru_body(b, bid - asplit, smem);
}

// ---------------- fused GAT attention ----------------
__launch_bounds__(256)
__global__ void k_attn(const unsigned short* __restrict__ SRC, const unsigned short* __restrict__ tgtbf,
                       const float* __restrict__ att, const int* __restrict__ list,
                       const int* __restrict__ offs, const float* __restrict__ batt,
                       unsigned short* __restrict__ msgDbf,
                       float* __restrict__ alphaG, int Dn, int F)
{
    __shared__ float tg[1024];
    __shared__ float alds[128*4];
    __shared__ float accs[4][256];
    int d = blockIdx.x;
    int tid = threadIdx.x;
    int w = tid >> 6, lane = tid & 63;
    for (int u = tid; u < 1024; u += 256) tg[u] = us2f(tgtbf[(size_t)d*1024 + u]);
    __syncthreads();
    int beg = offs[d], end = offs[d+1];
    if (beg < 0) beg = 0; if (end > F) end = F; if (end < beg) end = beg;
    int c0 = w*256 + lane*4;
    float t0 = tg[c0], t1 = tg[c0+1], t2 = tg[c0+2], t3 = tg[c0+3];
    float a0 = att[c0], a1 = att[c0+1], a2 = att[c0+2], a3 = att[c0+3];
    float amax = -3.4e38f;
    for (int i=beg;i<end;i++){
        int f = list[i];
        ushort4 sv = *reinterpret_cast<const ushort4*>(SRC + (size_t)f*1024 + c0);
        float e0 = us2f(sv.x)+t0, e1 = us2f(sv.y)+t1, e2 = us2f(sv.z)+t2, e3 = us2f(sv.w)+t3;
        e0 = e0>0.f?e0:0.2f*e0; e1 = e1>0.f?e1:0.2f*e1;
        e2 = e2>0.f?e2:0.2f*e2; e3 = e3>0.f?e3:0.2f*e3;
        float s = e0*a0 + e1*a1 + e2*a2 + e3*a3;
#pragma unroll
        for (int msk=1; msk<64; msk<<=1) s += __shfl_xor(s, msk);
        int li = i - beg;
        if (li < 128){ if (lane == 0) alds[li*4+w] = s; }
        else         { if (lane == 0) alphaG[(size_t)f*4+w] = s; }
        amax = fmaxf(amax, s);
    }
    __syncthreads();
    float wsum = 0.f;
    for (int i=beg;i<end;i++){
        int li = i - beg;
        float a = (li < 128) ? alds[li*4+w] : alphaG[(size_t)list[i]*4+w];
        wsum += expf(a - amax);
    }
    float iws = 1.f/(wsum + 1e-16f);
    float acc[4] = {0,0,0,0};
    for (int i=beg;i<end;i++){
        int f = list[i];
        int li = i - beg;
        float a = (li < 128) ? alds[li*4+w] : alphaG[(size_t)f*4+w];
        float p = expf(a - amax)*iws;
        ushort4 sv = *reinterpret_cast<const ushort4*>(SRC + (size_t)f*1024 + c0);
        acc[0] += p*us2f(sv.x); acc[1] += p*us2f(sv.y);
        acc[2] += p*us2f(sv.z); acc[3] += p*us2f(sv.w);
    }
#pragma unroll
    for (int j=0;j<4;j++) accs[w][lane*4+j] = acc[j];
    __syncthreads();
    if (tid < 256){
        float m = (accs[0][tid]+accs[1][tid]+accs[2][tid]+accs[3][tid])*0.25f + batt[tid];
        msgDbf[(size_t)d*256 + tid] = f2b(m);
    }
}

// ---------------- fused phiC recurrence: 8 services/block, bf16 gi ----------------
__launch_bounds__(512)
__global__ void k_recur(float* __restrict__ h_srv, const unsigned short* __restrict__ giFb,
                        const unsigned short* __restrict__ Whi,
                        const unsigned short* __restrict__ Wlo,
                        const float* __restrict__ bhh,
                        const int* __restrict__ inv,
                        unsigned short* __restrict__ out_f_bf,
                        int S, int L, int F)
{
    __shared__ float hs[8][129];
    __shared__ alignas(16) unsigned short hsHi[16*128];
    __shared__ alignas(16) unsigned short hsLo[16*128];
    __shared__ float ghs[16][385];
    __shared__ int fLoc[16][8];
    int tid = threadIdx.x;
    int l = tid & 63, w = tid >> 6;
    int lane15 = l & 15, lhi = l >> 4;
    int s0 = blockIdx.x * 8;
    for (int u = tid; u < 2048; u += 512){
        int s=u>>7,k=u&127;
        int ksw = k ^ ((s & 7) << 3);
        if (s < 8){
            float v = h_srv[(size_t)(s0+s)*128+k];
            hs[s][k] = v;
            unsigned short hb = f2b(v);
            hsHi[s*128 + ksw] = hb;
            hsLo[s*128 + ksw] = f2b(v - us2f(hb));
        } else {
            hsHi[s*128 + ksw] = 0;
            hsLo[s*128 + ksw] = 0;
        }
    }
    if (tid < 128) fLoc[tid>>3][tid&7] = inv[(size_t)(s0+(tid&7))*L + (tid>>3)];
    bf16x8 wHi[3][4], wLo[3][4];
#pragma unroll
    for (int ct=0; ct<3; ++ct){
        int col = w*48 + ct*16 + lane15;
#pragma unroll
        for (int ks=0; ks<4; ++ks){
            size_t off = (size_t)col*128 + ks*32 + lhi*8;
            wHi[ct][ks] = *reinterpret_cast<const bf16x8*>(Whi + off);
            wLo[ct][ks] = *reinterpret_cast<const bf16x8*>(Wlo + off);
        }
    }
    __syncthreads();
    for (int t=0;t<L;++t){
        bf16x8 hHi[4], hLo[4];
#pragma unroll
        for (int ks=0; ks<4; ++ks){
            int ek = ks*32 + lhi*8;
            int off = lane15*128 + (ek ^ ((lane15 & 7) << 3));
            hHi[ks] = *reinterpret_cast<const bf16x8*>(&hsHi[off]);
            hLo[ks] = *reinterpret_cast<const bf16x8*>(&hsLo[off]);
        }
#pragma unroll
        for (int ct=0; ct<3; ++ct){
            f32x4 acc = (f32x4){0.f,0.f,0.f,0.f};
#pragma unroll
            for (int ks=0; ks<4; ++ks){
                acc = __builtin_amdgcn_mfma_f32_16x16x32_bf16(hHi[ks], wHi[ct][ks], acc, 0,0,0);
                acc = __builtin_amdgcn_mfma_f32_16x16x32_bf16(hLo[ks], wHi[ct][ks], acc, 0,0,0);
                acc = __builtin_amdgcn_mfma_f32_16x16x32_bf16(hHi[ks], wLo[ct][ks], acc, 0,0,0);
            }
            int col = w*48 + ct*16 + lane15;
            float bb = bhh[col];
#pragma unroll
            for (int v=0; v<4; ++v){
                ghs[lhi*4 + v][col] = acc[v] + bb;
            }
        }
        __syncthreads();
        for (int u = tid; u < 1024; u += 512){
            int s=u>>7, k=u&127; int f = fLoc[t][s];
            if (f >= 0 && f < F){
                const unsigned short* gp = giFb + (size_t)f*384;
                float r  = sigf(us2f(gp[k])     + ghs[s][k]);
                float zz = sigf(us2f(gp[128+k]) + ghs[s][128+k]);
                float n  = tanhf(us2f(gp[256+k]) + r*ghs[s][256+k]);
                float hn = (1.f-zz)*n + zz*hs[s][k];
                hs[s][k] = hn;
                unsigned short hb = f2b(hn);
                int ksw = k ^ ((s & 7) << 3);
                hsHi[s*128 + ksw] = hb;
                hsLo[s*128 + ksw] = f2b(hn - us2f(hb));
                out_f_bf[(size_t)f*128+k] = hb;
            }
        }
        __syncthreads();
    }
    for (int u = tid; u < 1024; u += 512){ int s=u>>7,k=u&127; h_srv[(size_t)(s0+s)*128+k] = hs[s][k]; }
}

__global__ void k_count(const int* __restrict__ row, int* __restrict__ counts, int F, int Dn)
{ int f = blockIdx.x*blockDim.x + threadIdx.x; if (f < F) atomicAdd(&counts[clampi(row[f],0,Dn-1)], 1); }

__global__ void k_scan(const int* __restrict__ counts, int* __restrict__ offs, int D)
{
    __shared__ int part[257];
    int tid = threadIdx.x;
    int per = (D + 255) / 256;
    int s = 0;
    for (int i=0;i<per;i++){ int idx = tid*per+i; if (idx < D) s += counts[idx]; }
    part[tid] = s;
    __syncthreads();
    if (tid == 0){
        int acc = 0;
        for (int i=0;i<256;i++){ int v = part[i]; part[i] = acc; acc += v; }
        part[256] = acc;
    }
    __syncthreads();
    int acc = part[tid];
    for (int i=0;i<per;i++){ int idx = tid*per+i; if (idx < D){ offs[idx] = acc; acc += counts[idx]; } }
    if (tid == 0) offs[D] = part[256];
}

__global__ void k_fill(const int* __restrict__ row, const int* __restrict__ offs,
                       int* __restrict__ cursor, int* __restrict__ list, int F, int Dn)
{
    int f = blockIdx.x*blockDim.x + threadIdx.x;
    if (f >= F) return;
    int r = clampi(row[f],0,Dn-1);
    int p = atomicAdd(&cursor[r], 1);
    int pos = offs[r]+p;
    if (pos >= 0 && pos < F) list[pos] = f;
}

__global__ void k_build_inv(const int* __restrict__ fs, const int* __restrict__ fp,
                            int* __restrict__ inv, int F, int L, int S)
{
    int f = blockIdx.x*blockDim.x + threadIdx.x;
    if (f >= F) return;
    inv[clampi(fs[f],0,S-1)*L + clampi(fp[f],0,L-1)] = f;
}

__global__ void k_pool_add(const unsigned short* __restrict__ fragBf, const int* __restrict__ fs,
                           float* __restrict__ pooled, int F, int S)
{
    int t = blockIdx.x*blockDim.x + threadIdx.x;
    int i = t >> 7, j = t & 127;
    if (i >= F) return;
    atomicAdd(&pooled[(size_t)clampi(fs[i],0,S-1)*128 + j], us2f(fragBf[(size_t)i*128 + j]));
}

__global__ void k_pool_div(float* __restrict__ pooled, const int* __restrict__ lengths, int S)
{
    int t = blockIdx.x*blockDim.x + threadIdx.x;
    int i = t >> 7, j = t & 127;
    if (i >= S) return;
    int l = lengths[i]; if (l < 1) l = 1;
    pooled[(size_t)i*128 + j] /= (float)l;
}

__global__ void k_dot_out(const float* __restrict__ H, const float* __restrict__ W3,
                          const float* __restrict__ b3, float* __restrict__ outv, int off)
{
    __shared__ float red[256];
    int s = blockIdx.x, tid = threadIdx.x;
    red[tid] = H[(size_t)s*256 + tid] * W3[tid];
    __syncthreads();
    for (int st=128; st; st>>=1){ if (tid < st) red[tid] += red[tid+st]; __syncthreads(); }
    if (tid == 0) outv[off + s] = red[0] + b3[0];
}

// =====================================================================================
extern "C" void kernel_launch(void* const* d_in, const int* in_sizes, int n_in,
                              void* d_out, int out_size, void* d_ws, size_t ws_size,
                              hipStream_t stream)
{
    (void)n_in; (void)out_size; (void)ws_size;
    const float* realnode = (const float*)d_in[0];
    const float* arr      = (const float*)d_in[1];
    const int* r_exe   = (const int*)d_in[2];
    const int* r_idev  = (const int*)d_in[3];
    const int* r_ifrag = (const int*)d_in[4];
    const int* r_fdn   = (const int*)d_in[5];
    const int* r_fdr   = (const int*)d_in[6];
    const int* r_len   = (const int*)d_in[7];
    const int* r_fsvc  = (const int*)d_in[8];
    const int* r_fpos  = (const int*)d_in[9];
    const float *W_dev=(const float*)d_in[10], *b_dev=(const float*)d_in[11];
    const float *W_frg=(const float*)d_in[12], *b_frg=(const float*)d_in[13];
    const float *W_srv=(const float*)d_in[14], *b_srv=(const float*)d_in[15];
    const float *C_Wih=(const float*)d_in[16], *C_Whh=(const float*)d_in[17], *C_bih=(const float*)d_in[18], *C_bhh=(const float*)d_in[19];
    const float *F_Wih=(const float*)d_in[20], *F_Whh=(const float*)d_in[21], *F_bih=(const float*)d_in[22], *F_bhh=(const float*)d_in[23];
    const float *D_Wih=(const float*)d_in[24], *D_Whh=(const float*)d_in[25], *D_bih=(const float*)d_in[26], *D_bhh=(const float*)d_in[27];
    const float *W_src=(const float*)d_in[28], *b_src=(const float*)d_in[29];
    const float *W_tgt=(const float*)d_in[30], *b_tgt=(const float*)d_in[31];
    const float *att=(const float*)d_in[32], *bias_att=(const float*)d_in[33];
    const float *Wt1=(const float*)d_in[34], *bt1=(const float*)d_in[35], *Wt2=(const float*)d_in[36], *bt2=(const float*)d_in[37], *Wt3=(const float*)d_in[38], *bt3=(const float*)d_in[39];
    const float *Wl1=(const float*)d_in[40], *bl1=(const float*)d_in[41], *Wl2=(const float*)d_in[42], *bl2=(const float*)d_in[43], *Wl3=(const float*)d_in[44], *bl3=(const float*)d_in[45];
    float* outp = (float*)d_out;

    const int S  = in_sizes[7];
    const int Dn = in_sizes[3];
    const int F  = in_sizes[4];
    const int L  = in_sizes[2] / (2*S);
    const int nreal = in_sizes[0]/5;
    const int nodes = nreal + 1;
    const int NIT = 3;

    char* wp = (char*)d_ws;
    auto alloc = [&](size_t nelem)->float*{
        float* p = (float*)wp;
        wp += ((nelem*4 + 255)/256)*256;
        return p;
    };
    float* h_srv  = alloc((size_t)S*128);
    float* alphaB = alloc((size_t)F*4);
    float* UNION  = alloc((size_t)F*512);
    unsigned short* giFb = (unsigned short*)UNION;
    unsigned short* SRC  = (unsigned short*)UNION;
    float* Z      = alloc((size_t)Dn*1024);
    float* TGTf   = alloc((size_t)Dn*512);
    unsigned short* TGT = (unsigned short*)TGTf;
    float* pooled = alloc((size_t)S*128);
    unsigned short* state_bf = (unsigned short*)alloc((size_t)nodes*64);
    unsigned short* out_f_bf = (unsigned short*)alloc((size_t)F*64);
    unsigned short* fragA_bf = (unsigned short*)alloc((size_t)F*64);
    unsigned short* devA_bf  = (unsigned short*)alloc((size_t)Dn*64);
    unsigned short* msgD_bf  = (unsigned short*)alloc((size_t)Dn*128);
    unsigned short* tCWih   = (unsigned short*)alloc(384*256/2);
    unsigned short* tCWhhHi = (unsigned short*)alloc(384*128/2);
    unsigned short* tCWhhLo = (unsigned short*)alloc(384*128/2);
    unsigned short* tFWih   = (unsigned short*)alloc(384*256/2);
    unsigned short* tFWhh   = (unsigned short*)alloc(384*128/2);
    unsigned short* tDWih   = (unsigned short*)alloc(384*256/2);
    unsigned short* tDWhh   = (unsigned short*)alloc(384*128/2);
    unsigned short* tWtgt   = (unsigned short*)alloc(1024*128/2);
    unsigned short* tWsrc   = (unsigned short*)alloc(1024*256/2);
    int* cExe   = (int*)alloc((size_t)S*2*L);
    int* cIdev  = (int*)alloc((size_t)Dn);
    int* cIfrag = (int*)alloc((size_t)F);
    int* cFdn   = (int*)alloc((size_t)F);
    int* cFdr   = (int*)alloc((size_t)F);
    int* cLen   = (int*)alloc((size_t)S);
    int* cFsvc  = (int*)alloc((size_t)F);
    int* cFpos  = (int*)alloc((size_t)F);
    int* inv    = (int*)alloc((size_t)S*L);
    int* counts = (int*)alloc((size_t)Dn);
    int* offs   = (int*)alloc((size_t)Dn+1);
    int* cursor = (int*)alloc((size_t)Dn);
    int* list   = (int*)alloc((size_t)F);

    const int* det = r_idev;
    auto cvt = [&](const int* src, int* dst, int n){
        k_cvt<<<dim3((n+255)/256),256,0,stream>>>(src, dst, n, det);
    };
    cvt(r_exe,  cExe,  S*2*L);
    cvt(r_idev, cIdev, Dn);
    cvt(r_ifrag,cIfrag,F);
    cvt(r_fdn,  cFdn,  F);
    cvt(r_fdr,  cFdr,  F);
    cvt(r_len,  cLen,  S);
    cvt(r_fsvc, cFsvc, F);
    cvt(r_fpos, cFpos, F);

    k_wt<<<dim3((98304+255)/256),256,0,stream>>>(C_Wih, tCWih, 384, 8, 255, 98304);
    k_wt2<<<dim3((49152+255)/256),256,0,stream>>>(C_Whh, tCWhhHi, tCWhhLo, 384, 7, 127, 49152);
    k_wt<<<dim3((98304+255)/256),256,0,stream>>>(F_Wih, tFWih, 384, 8, 255, 98304);
    k_wt<<<dim3((49152+255)/256),256,0,stream>>>(F_Whh, tFWhh, 384, 7, 127, 49152);
    k_wt<<<dim3((98304+255)/256),256,0,stream>>>(D_Wih, tDWih, 384, 8, 255, 98304);
    k_wt<<<dim3((49152+255)/256),256,0,stream>>>(D_Whh, tDWhh, 384, 7, 127, 49152);
    k_wt<<<dim3((131072+255)/256),256,0,stream>>>(W_tgt, tWtgt, 1024, 7, 127, 131072);
    k_wt<<<dim3((262144+255)/256),256,0,stream>>>(W_src, tWsrc, 1024, 8, 255, 262144);

    hipMemsetAsync(state_bf, 0, (size_t)nodes*128*2, stream);
    hipMemsetAsync(inv, 0xFF, (size_t)S*L*4, stream);
    hipMemsetAsync(counts, 0, (size_t)Dn*4, stream);
    hipMemsetAsync(cursor, 0, (size_t)Dn*4, stream);

    k_proj5<<<dim3((Dn*128+255)/256),256,0,stream>>>(realnode, W_dev, b_dev, cIdev, cIdev,
        nullptr, state_bf, nullptr, devA_bf, Dn, nreal, nodes);
    k_proj5<<<dim3(((size_t)F*128+255)/256),256,0,stream>>>(realnode, W_frg, b_frg, cIfrag, cIfrag,
        nullptr, state_bf, nullptr, fragA_bf, F, nreal, nodes);
    k_proj5<<<dim3((S*128+255)/256),256,0,stream>>>(arr, W_srv, b_srv, nullptr, nullptr,
        h_srv, nullptr, nullptr, nullptr, S, S, nodes);
    k_build_inv<<<dim3((F+255)/256),256,0,stream>>>(cFsvc, cFpos, inv, F, L, S);
    k_count<<<dim3((F+255)/256),256,0,stream>>>(cFdr, counts, F, Dn);
    k_scan<<<1,256,0,stream>>>(counts, offs, Dn);
    k_fill<<<dim3((F+255)/256),256,0,stream>>>(cFdr, offs, cursor, list, F, Dn);

    const int nrF = F/128, nrD = Dn/128;
    MJob jGi  = { state_bf, state_bf, cIfrag, cFdn, tCWih, C_bih, giFb, 384, 256, 2, nrF, 1.f };
    MJob jTgt = { devA_bf, devA_bf, nullptr, nullptr, tWtgt, b_tgt, TGT, 1024, 128, 2, nrD, 1.f };
    MJob jSrc = { out_f_bf, fragA_bf, nullptr, nullptr, tWsrc, b_src, SRC, 1024, 256, 2, nrF, 1.f };
    GJob jF = { out_f_bf, state_bf, nullptr, cFdn, 128, tFWih, tFWhh, F_bih, F_bhh,
                fragA_bf, state_bf, cIfrag, F, nodes };
    GJob jD = { msgD_bf, nullptr, nullptr, nullptr, 256, tDWih, tDWhh, D_bih, D_bhh,
                devA_bf, state_bf, cIdev, Dn, nodes };

    for (int it=0; it<NIT; ++it){
        mm2two<<<dim3(3*nrF + 8*nrD),256,0,stream>>>(jGi, jTgt, 3*nrF);
        k_recur<<<dim3(S/8),512,0,stream>>>(h_srv, giFb, tCWhhHi, tCWhhLo, C_bhh, inv,
            out_f_bf, S, L, F);
        mm2one<<<dim3(8*nrF),256,0,stream>>>(jSrc);
        k_attn<<<dim3(Dn),256,0,stream>>>(SRC, TGT, att, list, offs, bias_att,
            msgD_bf, alphaB, Dn, F);
        gru2<<<dim3(nrF + nrD),512,0,stream>>>(jF, jD, nrF);
    }

    // readout
    hipMemsetAsync(pooled, 0, (size_t)S*128*4, stream);
    k_pool_add<<<dim3(((size_t)F*128+255)/256),256,0,stream>>>(fragA_bf, cFsvc, pooled, F, S);
    k_pool_div<<<dim3((S*128+255)/256),256,0,stream>>>(pooled, cLen, S);
    float* h1 = (float*)TGTf;
    k_mm<<<dim3(256/128, S/128),256,0,stream>>>(pooled, 128, Wl1, 256, bl1, h1, S, 256, 128, 1, 1.f, 0);
    k_mm<<<dim3(256/128, S/128),256,0,stream>>>(h1, 256, Wl2, 256, bl2, Z, S, 256, 256, 1, 1.f, 0);
    k_dot_out<<<dim3(S),256,0,stream>>>(Z, Wl3, bl3, outp, 0);
    k_mm<<<dim3(256/128, S/128),256,0,stream>>>(h_srv, 128, Wt1, 256, bt1, h1, S, 256, 128, 1, 1.f, 0);
    k_mm<<<dim3(256/128, S/128),256,0,stream>>>(h1, 256, Wt2, 256, bt2, Z, S, 256, 256, 1, 1.f, 0);
    k_dot_out<<<dim3(S),256,0,stream>>>(Z, Wt3, bt3, outp, S);
}

// Round 20
// 717.002 us; speedup vs baseline: 1.2862x; 1.1227x over previous
//
#include <hip/hip_runtime.h>
#include <hip/hip_bf16.h>

typedef __attribute__((ext_vector_type(8))) short bf16x8;
typedef __attribute__((ext_vector_type(4))) float f32x4;

__device__ __forceinline__ float sigf(float x){ return 1.0f/(1.0f+expf(-x)); }
__device__ __forceinline__ int clampi(int v, int lo, int hi){ return v<lo?lo:(v>hi?hi:v); }
__device__ __forceinline__ unsigned short f2b(float f){
    __hip_bfloat16 h = __float2bfloat16(f);
    return *reinterpret_cast<unsigned short*>(&h);
}
__device__ __forceinline__ float us2f(unsigned short u){ return __uint_as_float(((unsigned)u)<<16); }

__device__ __forceinline__ void gload16(const void* g, void* l){
    __builtin_amdgcn_global_load_lds((const __attribute__((address_space(1))) void*)g,
                                     (__attribute__((address_space(3))) void*)l, 16, 0, 0);
}

// ---- int64/int32 tolerant index conversion ----
__global__ void k_cvt(const int* __restrict__ src, int* __restrict__ dst, int n,
                      const int* __restrict__ det)
{
    int i = blockIdx.x*blockDim.x + threadIdx.x;
    if (i >= n) return;
    int stride = (det[1] == 0) ? 2 : 1;
    dst[i] = src[(size_t)i*stride];
}

__global__ void k_wt(const float* __restrict__ W, unsigned short* __restrict__ Wt,
                     int N, int kshift, int kmask, int total)
{
    int idx = blockIdx.x*blockDim.x + threadIdx.x;
    if (idx >= total) return;
    int n = idx >> kshift, k = idx & kmask;
    Wt[idx] = f2b(W[(size_t)k*N + n]);
}

__global__ void k_wt2(const float* __restrict__ W, unsigned short* __restrict__ Whi,
                      unsigned short* __restrict__ Wlo, int N, int kshift, int kmask, int total)
{
    int idx = blockIdx.x*blockDim.x + threadIdx.x;
    if (idx >= total) return;
    int n = idx >> kshift, k = idx & kmask;
    float v = W[(size_t)k*N + n];
    unsigned short hi = f2b(v);
    Whi[idx] = hi;
    Wlo[idx] = f2b(v - us2f(hi));
}

// ---------------- init projections ----------------
__global__ void k_proj5(const float* __restrict__ X, const float* __restrict__ W,
                        const float* __restrict__ bias,
                        const int* __restrict__ gidx, const int* __restrict__ sidx,
                        float* __restrict__ out, unsigned short* __restrict__ outBf,
                        float* __restrict__ out2, unsigned short* __restrict__ out2Bf,
                        int M, int nrows, int nodes)
{
    int t = blockIdx.x*blockDim.x + threadIdx.x;
    int i = t >> 7, j = t & 127;
    if (i >= M) return;
    int src = gidx ? clampi(gidx[i]-1, 0, nrows-1) : i;
    const float* xp = X + (size_t)src*5;
    float acc = bias[j];
#pragma unroll
    for (int k=0;k<5;k++) acc += xp[k] * W[k*128+j];
    int dr = sidx ? clampi(sidx[i], 0, nodes-1) : i;
    if (out)   out[(size_t)dr*128 + j] = acc;
    if (outBf) outBf[(size_t)dr*128 + j] = f2b(acc);
    if (out2)  out2[(size_t)i*128 + j] = acc;
    if (out2Bf) out2Bf[(size_t)i*128 + j] = f2b(acc);
}

// ---------------- f32 tiled GEMM (readout heads only) ----------------
__launch_bounds__(256)
__global__ void k_mm(const float* __restrict__ A0, int lda,
                     const float* __restrict__ B, int ldb,
                     const float* __restrict__ bias, float* __restrict__ C,
                     int M, int N, int K, int relu, float scale, int accum)
{
    __shared__ float As[16][132];
    __shared__ float Bs[16][132];
    int tid = threadIdx.x;
    int tx = tid & 15, ty = tid >> 4;
    int row0 = blockIdx.y * 128, col0 = blockIdx.x * 128;
    float acc[8][8] = {};
    for (int k0 = 0; k0 < K; k0 += 16){
#pragma unroll
        for (int q = 0; q < 2; ++q){
            int idx = tid + q*256;
            int r = idx >> 2, k4 = (idx & 3) * 4;
            const float* src = A0 + (size_t)(row0+r)*lda + k0 + k4;
            float4 v = *reinterpret_cast<const float4*>(src);
            As[k4+0][r]=v.x; As[k4+1][r]=v.y; As[k4+2][r]=v.z; As[k4+3][r]=v.w;
        }
#pragma unroll
        for (int q = 0; q < 2; ++q){
            int idx = tid + q*256;
            int kb = idx >> 5, n4 = (idx & 31) * 4;
            float4 v = *reinterpret_cast<const float4*>(B + (size_t)(k0+kb)*ldb + col0 + n4);
            *reinterpret_cast<float4*>(&Bs[kb][n4]) = v;
        }
        __syncthreads();
#pragma unroll
        for (int k = 0; k < 16; ++k){
            float a[8], b[8];
            *(float4*)&a[0] = *(const float4*)&As[k][ty*8];
            *(float4*)&a[4] = *(const float4*)&As[k][ty*8+4];
            *(float4*)&b[0] = *(const float4*)&Bs[k][tx*8];
            *(float4*)&b[4] = *(const float4*)&Bs[k][tx*8+4];
#pragma unroll
            for (int i=0;i<8;i++)
#pragma unroll
                for (int j=0;j<8;j++) acc[i][j] += a[i]*b[j];
        }
        __syncthreads();
    }
    float bb[8];
#pragma unroll
    for (int j=0;j<8;j++) bb[j] = bias ? bias[col0+tx*8+j] : 0.f;
#pragma unroll
    for (int i=0;i<8;i++){
        float* cp = C + (size_t)(row0+ty*8+i)*N + col0 + tx*8;
#pragma unroll
        for (int jq=0;jq<2;jq++){
            float4 prev = accum ? *(const float4*)(cp+jq*4) : make_float4(0,0,0,0);
            float o[4];
#pragma unroll
            for (int c=0;c<4;c++){
                float u = acc[i][jq*4+c] + bb[jq*4+c];
                if (relu) u = fmaxf(u,0.f);
                o[c] = (&prev.x)[c] + scale*u;
            }
            *(float4*)(cp+jq*4) = make_float4(o[0],o[1],o[2],o[3]);
        }
    }
}

// ---------------- pipelined bf16 MFMA GEMM body (counted vmcnt, 2-barrier) ----------------
struct MJob {
    const unsigned short *A0, *A1;
    const int *i0, *i1;
    const unsigned short *Wt;
    const float *bias;
    void *C;
    int N, K, epi, nrow;
    float scale;
};

#define MM2_SMEM 67840

__device__ __forceinline__ void mm2_body(const MJob J, int bid, char* smem)
{
    unsigned short* AsB = (unsigned short*)smem;
    unsigned short* BsB = AsB + 16384;
    int tid = threadIdx.x;
    int l = tid & 63, w = tid >> 6;
    int wr = w >> 1, wc = w & 1;
    int row0 = (bid % J.nrow) * 128, col0 = (bid / J.nrow) * 128;
    int nK = J.K >> 6;

    f32x4 acc[4][4];
#pragma unroll
    for (int m=0;m<4;m++)
#pragma unroll
        for (int n=0;n<4;n++) acc[m][n] = (f32x4){0.f,0.f,0.f,0.f};

    auto stage = [&](int buf, int k0){
        unsigned short* As = AsB + buf*8192;
        unsigned short* Bs = BsB + buf*8192;
#pragma unroll
        for (int q=0;q<4;q++){
            int slot = q*256 + w*64 + l;
            int r = slot >> 3, c8 = slot & 7;
            int g8 = c8 ^ (r & 7);
            int row; const unsigned short* base; int kl;
            if (k0 < 128){ row = J.i0 ? J.i0[row0+r] : (row0+r); base = J.A0; kl = k0; }
            else         { row = J.i1 ? J.i1[row0+r] : (row0+r); base = J.A1; kl = k0-128; }
            const char* g = (const char*)(base + (size_t)row*128 + kl) + g8*16;
            gload16(g, (void*)&As[(size_t)(q*256 + w*64)*8]);
        }
#pragma unroll
        for (int q=0;q<4;q++){
            int slot = q*256 + w*64 + l;
            int n = slot >> 3, kc = slot & 7;
            int g8 = kc ^ (n & 7);
            const char* g = (const char*)(J.Wt + (size_t)(col0+n)*J.K + k0) + g8*16;
            gload16(g, (void*)&Bs[(size_t)(q*256 + w*64)*8]);
        }
    };

    stage(0, 0);
    for (int ks=0; ks<nK; ++ks){
        int cur = ks & 1;
        if (ks+1 < nK){
            stage(cur^1, (ks+1)*64);
            asm volatile("s_waitcnt vmcnt(8)" ::: "memory");
        } else {
            asm volatile("s_waitcnt vmcnt(0)" ::: "memory");
        }
        __builtin_amdgcn_s_barrier();
        __builtin_amdgcn_sched_barrier(0);
        unsigned short* As = AsB + cur*8192;
        unsigned short* Bs = BsB + cur*8192;
#pragma unroll
        for (int kk = 0; kk < 2; ++kk){
            int ek = kk*32 + (l >> 4) * 8;
            bf16x8 af[4], bf[4];
#pragma unroll
            for (int m=0;m<4;m++){
                int r = wr*64 + m*16 + (l & 15);
                af[m] = *reinterpret_cast<const bf16x8*>(&As[r*64 + (ek ^ ((r & 7) << 3))]);
            }
#pragma unroll
            for (int n=0;n<4;n++){
                int c = wc*64 + n*16 + (l & 15);
                bf[n] = *reinterpret_cast<const bf16x8*>(&Bs[c*64 + (ek ^ ((c & 7) << 3))]);
            }
#pragma unroll
            for (int m=0;m<4;m++)
#pragma unroll
                for (int n=0;n<4;n++)
                    acc[m][n] = __builtin_amdgcn_mfma_f32_16x16x32_bf16(af[m], bf[n], acc[m][n], 0, 0, 0);
        }
        __builtin_amdgcn_sched_barrier(0);
        __builtin_amdgcn_s_barrier();
    }

    if (J.epi == 0){
        float* Ct = (float*)smem;
#pragma unroll
        for (int m=0;m<4;m++){
#pragma unroll
            for (int v=0;v<4;v++){
                int rl = wr*64 + m*16 + (l >> 4)*4 + v;
#pragma unroll
                for (int n=0;n<4;n++){
                    int c = wc*64 + n*16 + (l & 15);
                    Ct[rl*132 + c] = J.scale*acc[m][n][v] + (J.bias ? J.bias[col0+c] : 0.f);
                }
            }
        }
        __syncthreads();
#pragma unroll
        for (int q=0;q<16;q++){
            int idx = tid + q*256;
            int r = idx >> 5, c4 = (idx & 31)*4;
            float4 v = *reinterpret_cast<const float4*>(&Ct[r*132 + c4]);
            *reinterpret_cast<float4*>((float*)J.C + (size_t)(row0+r)*J.N + col0 + c4) = v;
        }
    } else {
        unsigned short* Cb = (unsigned short*)smem;
#pragma unroll
        for (int m=0;m<4;m++){
#pragma unroll
            for (int v=0;v<4;v++){
                int rl = wr*64 + m*16 + (l >> 4)*4 + v;
#pragma unroll
                for (int n=0;n<4;n++){
                    int c = wc*64 + n*16 + (l & 15);
                    Cb[rl*136 + c] = f2b(J.scale*acc[m][n][v] + (J.bias ? J.bias[col0+c] : 0.f));
                }
            }
        }
        __syncthreads();
#pragma unroll
        for (int q=0;q<8;q++){
            int idx = tid + q*256;
            int r = idx >> 4, c8 = (idx & 15)*8;
            uint4 v = *reinterpret_cast<const uint4*>(&Cb[r*136 + c8]);
            *reinterpret_cast<uint4*>((unsigned short*)J.C + (size_t)(row0+r)*J.N + col0 + c8) = v;
        }
    }
}

__launch_bounds__(256)
__global__ void mm2one(MJob a)
{
    __shared__ alignas(16) char smem[MM2_SMEM];
    mm2_body(a, blockIdx.x, smem);
}

__launch_bounds__(256)
__global__ void mm2two(MJob a, MJob b, int asplit)
{
    __shared__ alignas(16) char smem[MM2_SMEM];
    int bid = blockIdx.x;
    if (bid < asplit) mm2_body(a, bid, smem);
    else              mm2_body(b, bid - asplit, smem);
}

// ---------------- col-split fused GRU: 128 rows x 96 gate-cols per block, 56 KB LDS ----------------
struct GJob {
    const unsigned short *A0, *A1;
    const int *i0, *i1;
    int lda;
    const unsigned short *Wih, *Whh;
    const float *bih, *bhh;
    unsigned short *Hbf, *stateBf;
    const int *sidx;
    int M, nodes;
};

__device__ __forceinline__ void gru4_body(const GJob J, int rowTile, int chunk, char* smem)
{
    unsigned short* AsB = (unsigned short*)smem;      // 2 x 8192 ushort (32 KB)
    unsigned short* BsB = AsB + 2*8192;               // 2 x 6144 ushort (24 KB)
    int tid = threadIdx.x;
    int l = tid & 63, w = tid >> 6;
    int row0 = rowTile * 128;
    int cg0 = chunk * 32;
    // acc[n]: frag n covers local cols [n*16, n*16+16) of 96; gates r: n=0,1 z: n=2,3 n-gi: n=4,5
    f32x4 acc[6], accN[2];
#pragma unroll
    for (int n=0;n<6;n++) acc[n] = (f32x4){0.f,0.f,0.f,0.f};
#pragma unroll
    for (int n=0;n<2;n++) accN[n] = (f32x4){0.f,0.f,0.f,0.f};

    // fragment-order staging: A chunk i in [0,1024): frag=i>>6 (kk=frag>>3, wv=frag&7), lane=i&63
    //                         B chunk i in [0,768):  frag=i>>6 (kk=frag/6, n=frag%6), lane=i&63
    auto stage = [&](int buf, int st){
        int k0 = st*64;
        unsigned short* As = AsB + buf*8192;
        unsigned short* Bs = BsB + buf*6144;
#pragma unroll
        for (int q=0;q<2;q++){
            int i = (w*2+q)*64 + l;
            int frag = i >> 6, lane = i & 63;
            int kk = frag >> 3, wv = frag & 7;
            int r = wv*16 + (lane & 15);
            int slot = kk*4 + ((lane >> 4) & 3);
            const unsigned short* src;
            if (st < 4){
                if (J.i1){
                    if (k0 < 128){ int ri = J.i0 ? J.i0[row0+r] : (row0+r); src = J.A0 + (size_t)ri*128 + k0; }
                    else         { int ri = J.i1[row0+r]; src = J.A1 + (size_t)ri*128 + (k0-128); }
                } else {
                    src = J.A0 + (size_t)(row0+r)*J.lda + k0;
                }
            } else {
                src = J.Hbf + (size_t)(row0+r)*128 + (k0-256);
            }
            gload16((const char*)(src + slot*8), (void*)&As[(size_t)((w*2+q)*64)*8]);
        }
        if (w < 6){
#pragma unroll
            for (int q=0;q<2;q++){
                int i = (w*2+q)*64 + l;
                int frag = i >> 6, lane = i & 63;
                int kk = frag / 6, n = frag % 6;
                int c96 = n*16 + (lane & 15);
                int colg = (c96 >> 5)*128 + cg0 + (c96 & 31);
                int slot = kk*4 + ((lane >> 4) & 3);
                const unsigned short* src = (st < 4) ? (J.Wih + (size_t)colg*256 + k0)
                                                     : (J.Whh + (size_t)colg*128 + (k0-256));
                gload16((const char*)(src + slot*8), (void*)&Bs[(size_t)((w*2+q)*64)*8]);
            }
        }
    };

    stage(0, 0);
    for (int st=0; st<6; ++st){
        int cur = st & 1;
        if (st+1 < 6){
            stage(cur^1, st+1);
            if (w < 6) asm volatile("s_waitcnt vmcnt(4)" ::: "memory");
            else       asm volatile("s_waitcnt vmcnt(2)" ::: "memory");
        } else {
            asm volatile("s_waitcnt vmcnt(0)" ::: "memory");
        }
        __builtin_amdgcn_s_barrier();
        __builtin_amdgcn_sched_barrier(0);
        unsigned short* As = AsB + cur*8192;
        unsigned short* Bs = BsB + cur*6144;
        if (st < 4){
#pragma unroll
            for (int kk=0; kk<2; ++kk){
                bf16x8 af = *reinterpret_cast<const bf16x8*>(&As[(size_t)((kk*8 + w)*64 + l)*8]);
#pragma unroll
                for (int n=0;n<6;n++){
                    bf16x8 bf = *reinterpret_cast<const bf16x8*>(&Bs[(size_t)((kk*6 + n)*64 + l)*8]);
                    acc[n] = __builtin_amdgcn_mfma_f32_16x16x32_bf16(af, bf, acc[n], 0, 0, 0);
                }
            }
        } else {
#pragma unroll
            for (int kk=0; kk<2; ++kk){
                bf16x8 af = *reinterpret_cast<const bf16x8*>(&As[(size_t)((kk*8 + w)*64 + l)*8]);
#pragma unroll
                for (int n=0;n<6;n++){
                    bf16x8 bf = *reinterpret_cast<const bf16x8*>(&Bs[(size_t)((kk*6 + n)*64 + l)*8]);
                    if (n < 4) acc[n]     = __builtin_amdgcn_mfma_f32_16x16x32_bf16(af, bf, acc[n], 0, 0, 0);
                    else       accN[n-4]  = __builtin_amdgcn_mfma_f32_16x16x32_bf16(af, bf, accN[n-4], 0, 0, 0);
                }
            }
        }
        __builtin_amdgcn_sched_barrier(0);
        __builtin_amdgcn_s_barrier();
    }

    // ---- epilogue: 128 x 32 bf16 tile of H (this chunk's output cols) ----
    __syncthreads();
    unsigned short* Hb = (unsigned short*)smem;   // [128][40]
    {
        int r = tid >> 2, c8 = (tid & 3)*8;
        uint4 v = *reinterpret_cast<const uint4*>(J.Hbf + (size_t)(row0+r)*128 + cg0 + c8);
        *reinterpret_cast<uint4*>(&Hb[r*40 + c8]) = v;
    }
    __syncthreads();
#pragma unroll
    for (int v=0;v<4;v++){
        int rloc = w*16 + (l >> 4)*4 + v;
#pragma unroll
        for (int j=0;j<2;j++){
            int lc = j*16 + (l & 15);
            float rr = sigf(acc[j][v]    + J.bih[cg0+lc]     + J.bhh[cg0+lc]);
            float zz = sigf(acc[2+j][v]  + J.bih[128+cg0+lc] + J.bhh[128+cg0+lc]);
            float nn = tanhf(acc[4+j][v] + J.bih[256+cg0+lc] + rr*(accN[j][v] + J.bhh[256+cg0+lc]));
            float hv = us2f(Hb[rloc*40 + lc]);
            float hn = (1.f-zz)*nn + zz*hv;
            Hb[rloc*40 + lc] = f2b(hn);
        }
    }
    __syncthreads();
    {
        int r = tid >> 2, c8 = (tid & 3)*8;
        uint4 v = *reinterpret_cast<const uint4*>(&Hb[r*40 + c8]);
        *reinterpret_cast<uint4*>(J.Hbf + (size_t)(row0+r)*128 + cg0 + c8) = v;
        int st = clampi(J.sidx[row0+r],0,J.nodes-1);
        *reinterpret_cast<uint4*>(J.stateBf + (size_t)st*128 + cg0 + c8) = v;
    }
}

__launch_bounds__(512)
__global__ void gru4(GJob a, GJob b, int asplit)
{
    __shared__ alignas(16) char smem[57344];
    int bid = blockIdx.x;
    if (bid < asplit) gru4_body(a, bid >> 2, bid & 3, smem);
    else { bid -= asplit; gru4_body(b, bid >> 2, bid & 3, smem); }
}

// ---------------- fused GAT attention ----------------
__launch_bounds__(256)
__global__ void k_attn(const unsigned short* __restrict__ SRC, const unsigned short* __restrict__ tgtbf,
                       const float* __restrict__ att, const int* __restrict__ list,
                       const int* __restrict__ offs, const float* __restrict__ batt,
                       unsigned short* __restrict__ msgDbf,
                       float* __restrict__ alphaG, int Dn, int F)
{
    __shared__ float tg[1024];
    __shared__ float alds[128*4];
    __shared__ float accs[4][256];
    int d = blockIdx.x;
    int tid = threadIdx.x;
    int w = tid >> 6, lane = tid & 63;
    for (int u = tid; u < 1024; u += 256) tg[u] = us2f(tgtbf[(size_t)d*1024 + u]);
    __syncthreads();
    int beg = offs[d], end = offs[d+1];
    if (beg < 0) beg = 0; if (end > F) end = F; if (end < beg) end = beg;
    int c0 = w*256 + lane*4;
    float t0 = tg[c0], t1 = tg[c0+1], t2 = tg[c0+2], t3 = tg[c0+3];
    float a0 = att[c0], a1 = att[c0+1], a2 = att[c0+2], a3 = att[c0+3];
    float amax = -3.4e38f;
    for (int i=beg;i<end;i++){
        int f = list[i];
        ushort4 sv = *reinterpret_cast<const ushort4*>(SRC + (size_t)f*1024 + c0);
        float e0 = us2f(sv.x)+t0, e1 = us2f(sv.y)+t1, e2 = us2f(sv.z)+t2, e3 = us2f(sv.w)+t3;
        e0 = e0>0.f?e0:0.2f*e0; e1 = e1>0.f?e1:0.2f*e1;
        e2 = e2>0.f?e2:0.2f*e2; e3 = e3>0.f?e3:0.2f*e3;
        float s = e0*a0 + e1*a1 + e2*a2 + e3*a3;
#pragma unroll
        for (int msk=1; msk<64; msk<<=1) s += __shfl_xor(s, msk);
        int li = i - beg;
        if (li < 128){ if (lane == 0) alds[li*4+w] = s; }
        else         { if (lane == 0) alphaG[(size_t)f*4+w] = s; }
        amax = fmaxf(amax, s);
    }
    __syncthreads();
    float wsum = 0.f;
    for (int i=beg;i<end;i++){
        int li = i - beg;
        float a = (li < 128) ? alds[li*4+w] : alphaG[(size_t)list[i]*4+w];
        wsum += expf(a - amax);
    }
    float iws = 1.f/(wsum + 1e-16f);
    float acc[4] = {0,0,0,0};
    for (int i=beg;i<end;i++){
        int f = list[i];
        int li = i - beg;
        float a = (li < 128) ? alds[li*4+w] : alphaG[(size_t)f*4+w];
        float p = expf(a - amax)*iws;
        ushort4 sv = *reinterpret_cast<const ushort4*>(SRC + (size_t)f*1024 + c0);
        acc[0] += p*us2f(sv.x); acc[1] += p*us2f(sv.y);
        acc[2] += p*us2f(sv.z); acc[3] += p*us2f(sv.w);
    }
#pragma unroll
    for (int j=0;j<4;j++) accs[w][lane*4+j] = acc[j];
    __syncthreads();
    if (tid < 256){
        float m = (accs[0][tid]+accs[1][tid]+accs[2][tid]+accs[3][tid])*0.25f + batt[tid];
        msgDbf[(size_t)d*256 + tid] = f2b(m);
    }
}

// ---------------- fused phiC recurrence: 8 services/block, bf16 gi ----------------
__launch_bounds__(512)
__global__ void k_recur(float* __restrict__ h_srv, const unsigned short* __restrict__ giFb,
                        const unsigned short* __restrict__ Whi,
                        const unsigned short* __restrict__ Wlo,
                        const float* __restrict__ bhh,
                        const int* __restrict__ inv,
                        unsigned short* __restrict__ out_f_bf,
                        int S, int L, int F)
{
    __shared__ float hs[8][129];
    __shared__ alignas(16) unsigned short hsHi[16*128];
    __shared__ alignas(16) unsigned short hsLo[16*128];
    __shared__ float ghs[16][385];
    __shared__ int fLoc[16][8];
    int tid = threadIdx.x;
    int l = tid & 63, w = tid >> 6;
    int lane15 = l & 15, lhi = l >> 4;
    int s0 = blockIdx.x * 8;
    for (int u = tid; u < 2048; u += 512){
        int s=u>>7,k=u&127;
        int ksw = k ^ ((s & 7) << 3);
        if (s < 8){
            float v = h_srv[(size_t)(s0+s)*128+k];
            hs[s][k] = v;
            unsigned short hb = f2b(v);
            hsHi[s*128 + ksw] = hb;
            hsLo[s*128 + ksw] = f2b(v - us2f(hb));
        } else {
            hsHi[s*128 + ksw] = 0;
            hsLo[s*128 + ksw] = 0;
        }
    }
    if (tid < 128) fLoc[tid>>3][tid&7] = inv[(size_t)(s0+(tid&7))*L + (tid>>3)];
    bf16x8 wHi[3][4], wLo[3][4];
#pragma unroll
    for (int ct=0; ct<3; ++ct){
        int col = w*48 + ct*16 + lane15;
#pragma unroll
        for (int ks=0; ks<4; ++ks){
            size_t off = (size_t)col*128 + ks*32 + lhi*8;
            wHi[ct][ks] = *reinterpret_cast<const bf16x8*>(Whi + off);
            wLo[ct][ks] = *reinterpret_cast<const bf16x8*>(Wlo + off);
        }
    }
    __syncthreads();
    for (int t=0;t<L;++t){
        bf16x8 hHi[4], hLo[4];
#pragma unroll
        for (int ks=0; ks<4; ++ks){
            int ek = ks*32 + lhi*8;
            int off = lane15*128 + (ek ^ ((lane15 & 7) << 3));
            hHi[ks] = *reinterpret_cast<const bf16x8*>(&hsHi[off]);
            hLo[ks] = *reinterpret_cast<const bf16x8*>(&hsLo[off]);
        }
#pragma unroll
        for (int ct=0; ct<3; ++ct){
            f32x4 acc = (f32x4){0.f,0.f,0.f,0.f};
#pragma unroll
            for (int ks=0; ks<4; ++ks){
                acc = __builtin_amdgcn_mfma_f32_16x16x32_bf16(hHi[ks], wHi[ct][ks], acc, 0,0,0);
                acc = __builtin_amdgcn_mfma_f32_16x16x32_bf16(hLo[ks], wHi[ct][ks], acc, 0,0,0);
                acc = __builtin_amdgcn_mfma_f32_16x16x32_bf16(hHi[ks], wLo[ct][ks], acc, 0,0,0);
            }
            int col = w*48 + ct*16 + lane15;
            float bb = bhh[col];
#pragma unroll
            for (int v=0; v<4; ++v){
                ghs[lhi*4 + v][col] = acc[v] + bb;
            }
        }
        __syncthreads();
        for (int u = tid; u < 1024; u += 512){
            int s=u>>7, k=u&127; int f = fLoc[t][s];
            if (f >= 0 && f < F){
                const unsigned short* gp = giFb + (size_t)f*384;
                float r  = sigf(us2f(gp[k])     + ghs[s][k]);
                float zz = sigf(us2f(gp[128+k]) + ghs[s][128+k]);
                float n  = tanhf(us2f(gp[256+k]) + r*ghs[s][256+k]);
                float hn = (1.f-zz)*n + zz*hs[s][k];
                hs[s][k] = hn;
                unsigned short hb = f2b(hn);
                int ksw = k ^ ((s & 7) << 3);
                hsHi[s*128 + ksw] = hb;
                hsLo[s*128 + ksw] = f2b(hn - us2f(hb));
                out_f_bf[(size_t)f*128+k] = hb;
            }
        }
        __syncthreads();
    }
    for (int u = tid; u < 1024; u += 512){ int s=u>>7,k=u&127; h_srv[(size_t)(s0+s)*128+k] = hs[s][k]; }
}

__global__ void k_count(const int* __restrict__ row, int* __restrict__ counts, int F, int Dn)
{ int f = blockIdx.x*blockDim.x + threadIdx.x; if (f < F) atomicAdd(&counts[clampi(row[f],0,Dn-1)], 1); }

__global__ void k_scan(const int* __restrict__ counts, int* __restrict__ offs, int D)
{
    __shared__ int part[257];
    int tid = threadIdx.x;
    int per = (D + 255) / 256;
    int s = 0;
    for (int i=0;i<per;i++){ int idx = tid*per+i; if (idx < D) s += counts[idx]; }
    part[tid] = s;
    __syncthreads();
    if (tid == 0){
        int acc = 0;
        for (int i=0;i<256;i++){ int v = part[i]; part[i] = acc; acc += v; }
        part[256] = acc;
    }
    __syncthreads();
    int acc = part[tid];
    for (int i=0;i<per;i++){ int idx = tid*per+i; if (idx < D){ offs[idx] = acc; acc += counts[idx]; } }
    if (tid == 0) offs[D] = part[256];
}

__global__ void k_fill(const int* __restrict__ row, const int* __restrict__ offs,
                       int* __restrict__ cursor, int* __restrict__ list, int F, int Dn)
{
    int f = blockIdx.x*blockDim.x + threadIdx.x;
    if (f >= F) return;
    int r = clampi(row[f],0,Dn-1);
    int p = atomicAdd(&cursor[r], 1);
    int pos = offs[r]+p;
    if (pos >= 0 && pos < F) list[pos] = f;
}

__global__ void k_build_inv(const int* __restrict__ fs, const int* __restrict__ fp,
                            int* __restrict__ inv, int F, int L, int S)
{
    int f = blockIdx.x*blockDim.x + threadIdx.x;
    if (f >= F) return;
    inv[clampi(fs[f],0,S-1)*L + clampi(fp[f],0,L-1)] = f;
}

__global__ void k_pool_add(const unsigned short* __restrict__ fragBf, const int* __restrict__ fs,
                           float* __restrict__ pooled, int F, int S)
{
    int t = blockIdx.x*blockDim.x + threadIdx.x;
    int i = t >> 7, j = t & 127;
    if (i >= F) return;
    atomicAdd(&pooled[(size_t)clampi(fs[i],0,S-1)*128 + j], us2f(fragBf[(size_t)i*128 + j]));
}

__global__ void k_pool_div(float* __restrict__ pooled, const int* __restrict__ lengths, int S)
{
    int t = blockIdx.x*blockDim.x + threadIdx.x;
    int i = t >> 7, j = t & 127;
    if (i >= S) return;
    int l = lengths[i]; if (l < 1) l = 1;
    pooled[(size_t)i*128 + j] /= (float)l;
}

__global__ void k_dot_out(const float* __restrict__ H, const float* __restrict__ W3,
                          const float* __restrict__ b3, float* __restrict__ outv, int off)
{
    __shared__ float red[256];
    int s = blockIdx.x, tid = threadIdx.x;
    red[tid] = H[(size_t)s*256 + tid] * W3[tid];
    __syncthreads();
    for (int st=128; st; st>>=1){ if (tid < st) red[tid] += red[tid+st]; __syncthreads(); }
    if (tid == 0) outv[off + s] = red[0] + b3[0];
}

// =====================================================================================
extern "C" void kernel_launch(void* const* d_in, const int* in_sizes, int n_in,
                              void* d_out, int out_size, void* d_ws, size_t ws_size,
                              hipStream_t stream)
{
    (void)n_in; (void)out_size; (void)ws_size;
    const float* realnode = (const float*)d_in[0];
    const float* arr      = (const float*)d_in[1];
    const int* r_exe   = (const int*)d_in[2];
    const int* r_idev  = (const int*)d_in[3];
    const int* r_ifrag = (const int*)d_in[4];
    const int* r_fdn   = (const int*)d_in[5];
    const int* r_fdr   = (const int*)d_in[6];
    const int* r_len   = (const int*)d_in[7];
    const int* r_fsvc  = (const int*)d_in[8];
    const int* r_fpos  = (const int*)d_in[9];
    const float *W_dev=(const float*)d_in[10], *b_dev=(const float*)d_in[11];
    const float *W_frg=(const float*)d_in[12], *b_frg=(const float*)d_in[13];
    const float *W_srv=(const float*)d_in[14], *b_srv=(const float*)d_in[15];
    const float *C_Wih=(const float*)d_in[16], *C_Whh=(const float*)d_in[17], *C_bih=(const float*)d_in[18], *C_bhh=(const float*)d_in[19];
    const float *F_Wih=(const float*)d_in[20], *F_Whh=(const float*)d_in[21], *F_bih=(const float*)d_in[22], *F_bhh=(const float*)d_in[23];
    const float *D_Wih=(const float*)d_in[24], *D_Whh=(const float*)d_in[25], *D_bih=(const float*)d_in[26], *D_bhh=(const float*)d_in[27];
    const float *W_src=(const float*)d_in[28], *b_src=(const float*)d_in[29];
    const float *W_tgt=(const float*)d_in[30], *b_tgt=(const float*)d_in[31];
    const float *att=(const float*)d_in[32], *bias_att=(const float*)d_in[33];
    const float *Wt1=(const float*)d_in[34], *bt1=(const float*)d_in[35], *Wt2=(const float*)d_in[36], *bt2=(const float*)d_in[37], *Wt3=(const float*)d_in[38], *bt3=(const float*)d_in[39];
    const float *Wl1=(const float*)d_in[40], *bl1=(const float*)d_in[41], *Wl2=(const float*)d_in[42], *bl2=(const float*)d_in[43], *Wl3=(const float*)d_in[44], *bl3=(const float*)d_in[45];
    float* outp = (float*)d_out;

    const int S  = in_sizes[7];
    const int Dn = in_sizes[3];
    const int F  = in_sizes[4];
    const int L  = in_sizes[2] / (2*S);
    const int nreal = in_sizes[0]/5;
    const int nodes = nreal + 1;
    const int NIT = 3;

    char* wp = (char*)d_ws;
    auto alloc = [&](size_t nelem)->float*{
        float* p = (float*)wp;
        wp += ((nelem*4 + 255)/256)*256;
        return p;
    };
    float* h_srv  = alloc((size_t)S*128);
    float* alphaB = alloc((size_t)F*4);
    float* UNION  = alloc((size_t)F*512);
    unsigned short* giFb = (unsigned short*)UNION;
    unsigned short* SRC  = (unsigned short*)UNION;
    float* Z      = alloc((size_t)Dn*1024);
    float* TGTf   = alloc((size_t)Dn*512);
    unsigned short* TGT = (unsigned short*)TGTf;
    float* pooled = alloc((size_t)S*128);
    unsigned short* state_bf = (unsigned short*)alloc((size_t)nodes*64);
    unsigned short* out_f_bf = (unsigned short*)alloc((size_t)F*64);
    unsigned short* fragA_bf = (unsigned short*)alloc((size_t)F*64);
    unsigned short* devA_bf  = (unsigned short*)alloc((size_t)Dn*64);
    unsigned short* msgD_bf  = (unsigned short*)alloc((size_t)Dn*128);
    unsigned short* tCWih   = (unsigned short*)alloc(384*256/2);
    unsigned short* tCWhhHi = (unsigned short*)alloc(384*128/2);
    unsigned short* tCWhhLo = (unsigned short*)alloc(384*128/2);
    unsigned short* tFWih   = (unsigned short*)alloc(384*256/2);
    unsigned short* tFWhh   = (unsigned short*)alloc(384*128/2);
    unsigned short* tDWih   = (unsigned short*)alloc(384*256/2);
    unsigned short* tDWhh   = (unsigned short*)alloc(384*128/2);
    unsigned short* tWtgt   = (unsigned short*)alloc(1024*128/2);
    unsigned short* tWsrc   = (unsigned short*)alloc(1024*256/2);
    int* cExe   = (int*)alloc((size_t)S*2*L);
    int* cIdev  = (int*)alloc((size_t)Dn);
    int* cIfrag = (int*)alloc((size_t)F);
    int* cFdn   = (int*)alloc((size_t)F);
    int* cFdr   = (int*)alloc((size_t)F);
    int* cLen   = (int*)alloc((size_t)S);
    int* cFsvc  = (int*)alloc((size_t)F);
    int* cFpos  = (int*)alloc((size_t)F);
    int* inv    = (int*)alloc((size_t)S*L);
    int* counts = (int*)alloc((size_t)Dn);
    int* offs   = (int*)alloc((size_t)Dn+1);
    int* cursor = (int*)alloc((size_t)Dn);
    int* list   = (int*)alloc((size_t)F);

    const int* det = r_idev;
    auto cvt = [&](const int* src, int* dst, int n){
        k_cvt<<<dim3((n+255)/256),256,0,stream>>>(src, dst, n, det);
    };
    cvt(r_exe,  cExe,  S*2*L);
    cvt(r_idev, cIdev, Dn);
    cvt(r_ifrag,cIfrag,F);
    cvt(r_fdn,  cFdn,  F);
    cvt(r_fdr,  cFdr,  F);
    cvt(r_len,  cLen,  S);
    cvt(r_fsvc, cFsvc, F);
    cvt(r_fpos, cFpos, F);

    k_wt<<<dim3((98304+255)/256),256,0,stream>>>(C_Wih, tCWih, 384, 8, 255, 98304);
    k_wt2<<<dim3((49152+255)/256),256,0,stream>>>(C_Whh, tCWhhHi, tCWhhLo, 384, 7, 127, 49152);
    k_wt<<<dim3((98304+255)/256),256,0,stream>>>(F_Wih, tFWih, 384, 8, 255, 98304);
    k_wt<<<dim3((49152+255)/256),256,0,stream>>>(F_Whh, tFWhh, 384, 7, 127, 49152);
    k_wt<<<dim3((98304+255)/256),256,0,stream>>>(D_Wih, tDWih, 384, 8, 255, 98304);
    k_wt<<<dim3((49152+255)/256),256,0,stream>>>(D_Whh, tDWhh, 384, 7, 127, 49152);
    k_wt<<<dim3((131072+255)/256),256,0,stream>>>(W_tgt, tWtgt, 1024, 7, 127, 131072);
    k_wt<<<dim3((262144+255)/256),256,0,stream>>>(W_src, tWsrc, 1024, 8, 255, 262144);

    hipMemsetAsync(state_bf, 0, (size_t)nodes*128*2, stream);
    hipMemsetAsync(inv, 0xFF, (size_t)S*L*4, stream);
    hipMemsetAsync(counts, 0, (size_t)Dn*4, stream);
    hipMemsetAsync(cursor, 0, (size_t)Dn*4, stream);

    k_proj5<<<dim3((Dn*128+255)/256),256,0,stream>>>(realnode, W_dev, b_dev, cIdev, cIdev,
        nullptr, state_bf, nullptr, devA_bf, Dn, nreal, nodes);
    k_proj5<<<dim3(((size_t)F*128+255)/256),256,0,stream>>>(realnode, W_frg, b_frg, cIfrag, cIfrag,
        nullptr, state_bf, nullptr, fragA_bf, F, nreal, nodes);
    k_proj5<<<dim3((S*128+255)/256),256,0,stream>>>(arr, W_srv, b_srv, nullptr, nullptr,
        h_srv, nullptr, nullptr, nullptr, S, S, nodes);
    k_build_inv<<<dim3((F+255)/256),256,0,stream>>>(cFsvc, cFpos, inv, F, L, S);
    k_count<<<dim3((F+255)/256),256,0,stream>>>(cFdr, counts, F, Dn);
    k_scan<<<1,256,0,stream>>>(counts, offs, Dn);
    k_fill<<<dim3((F+255)/256),256,0,stream>>>(cFdr, offs, cursor, list, F, Dn);

    const int nrF = F/128, nrD = Dn/128;
    MJob jGi  = { state_bf, state_bf, cIfrag, cFdn, tCWih, C_bih, giFb, 384, 256, 2, nrF, 1.f };
    MJob jTgt = { devA_bf, devA_bf, nullptr, nullptr, tWtgt, b_tgt, TGT, 1024, 128, 2, nrD, 1.f };
    MJob jSrc = { out_f_bf, fragA_bf, nullptr, nullptr, tWsrc, b_src, SRC, 1024, 256, 2, nrF, 1.f };
    GJob jF = { out_f_bf, state_bf, nullptr, cFdn, 128, tFWih, tFWhh, F_bih, F_bhh,
                fragA_bf, state_bf, cIfrag, F, nodes };
    GJob jD = { msgD_bf, nullptr, nullptr, nullptr, 256, tDWih, tDWhh, D_bih, D_bhh,
                devA_bf, state_bf, cIdev, Dn, nodes };

    for (int it=0; it<NIT; ++it){
        mm2two<<<dim3(3*nrF + 8*nrD),256,0,stream>>>(jGi, jTgt, 3*nrF);
        k_recur<<<dim3(S/8),512,0,stream>>>(h_srv, giFb, tCWhhHi, tCWhhLo, C_bhh, inv,
            out_f_bf, S, L, F);
        mm2one<<<dim3(8*nrF),256,0,stream>>>(jSrc);
        k_attn<<<dim3(Dn),256,0,stream>>>(SRC, TGT, att, list, offs, bias_att,
            msgD_bf, alphaB, Dn, F);
        gru4<<<dim3(4*nrF + 4*nrD),512,0,stream>>>(jF, jD, 4*nrF);
    }

    // readout
    hipMemsetAsync(pooled, 0, (size_t)S*128*4, stream);
    k_pool_add<<<dim3(((size_t)F*128+255)/256),256,0,stream>>>(fragA_bf, cFsvc, pooled, F, S);
    k_pool_div<<<dim3((S*128+255)/256),256,0,stream>>>(pooled, cLen, S);
    float* h1 = (float*)TGTf;
    k_mm<<<dim3(256/128, S/128),256,0,stream>>>(pooled, 128, Wl1, 256, bl1, h1, S, 256, 128, 1, 1.f, 0);
    k_mm<<<dim3(256/128, S/128),256,0,stream>>>(h1, 256, Wl2, 256, bl2, Z, S, 256, 256, 1, 1.f, 0);
    k_dot_out<<<dim3(S),256,0,stream>>>(Z, Wl3, bl3, outp, 0);
    k_mm<<<dim3(256/128, S/128),256,0,stream>>>(h_srv, 128, Wt1, 256, bt1, h1, S, 256, 128, 1, 1.f, 0);
    k_mm<<<dim3(256/128, S/128),256,0,stream>>>(h1, 256, Wt2, 256, bt2, Z, S, 256, 256, 1, 1.f, 0);
    k_dot_out<<<dim3(S),256,0,stream>>>(Z, Wt3, bt3, outp, S);
}